// Round 1
// baseline (1128.728 us; speedup 1.0000x reference)
//
#include <hip/hip_runtime.h>

// ---------------------------------------------------------------------------
// GraphSAGE x3 (sum aggr) + global mean pool, fp32.
// Pipeline: build CSR over dst -> [agg -> fused GEMM relu(agg@Wl + h@Wr + b)] x3 -> pool
// ---------------------------------------------------------------------------

// ---------------- CSR build ----------------
__global__ void k_count(const int* __restrict__ dst, int* __restrict__ cnt, int E) {
    int e = blockIdx.x * 256 + threadIdx.x;
    if (e < E) atomicAdd(&cnt[dst[e]], 1);
}

__global__ void k_bsum(const int* __restrict__ cnt, int* __restrict__ bsum, int N) {
    __shared__ int sm[256];
    int i = blockIdx.x * 256 + threadIdx.x;
    sm[threadIdx.x] = (i < N) ? cnt[i] : 0;
    __syncthreads();
    for (int off = 128; off > 0; off >>= 1) {
        if (threadIdx.x < off) sm[threadIdx.x] += sm[threadIdx.x + off];
        __syncthreads();
    }
    if (threadIdx.x == 0) bsum[blockIdx.x] = sm[0];
}

// NB <= 256 (N=50000 -> NB=196)
__global__ void k_bscan(const int* __restrict__ bsum, int* __restrict__ boff, int NB) {
    __shared__ int sm[256];
    int t = threadIdx.x;
    int v = (t < NB) ? bsum[t] : 0;
    sm[t] = v;
    __syncthreads();
    for (int off = 1; off < 256; off <<= 1) {
        int add = (t >= off) ? sm[t - off] : 0;
        __syncthreads();
        sm[t] += add;
        __syncthreads();
    }
    if (t < NB) boff[t] = sm[t] - v;  // exclusive
}

__global__ void k_scan(const int* __restrict__ cnt, const int* __restrict__ boff,
                       int* __restrict__ rowptr, int* __restrict__ wpos, int N, int E) {
    __shared__ int sm[256];
    int t = threadIdx.x;
    int i = blockIdx.x * 256 + t;
    int v = (i < N) ? cnt[i] : 0;
    sm[t] = v;
    __syncthreads();
    for (int off = 1; off < 256; off <<= 1) {
        int add = (t >= off) ? sm[t - off] : 0;
        __syncthreads();
        sm[t] += add;
        __syncthreads();
    }
    int ex = sm[t] - v + boff[blockIdx.x];
    if (i < N) { rowptr[i] = ex; wpos[i] = ex; }
    if (i == 0) rowptr[N] = E;
}

__global__ void k_fill(const int* __restrict__ src, const int* __restrict__ dst,
                       int* __restrict__ wpos, int* __restrict__ csr, int E) {
    int e = blockIdx.x * 256 + threadIdx.x;
    if (e < E) {
        int p = atomicAdd(&wpos[dst[e]], 1);
        csr[p] = src[e];
    }
}

// ---------------- aggregation: agg[i] = sum_{e: dst==i} h[src[e]] ----------------
// 256-thread blocks = 4 waves, one wave per node. VEC: 4 -> float4 (D=256),
// 2 -> float2 (D=128), 1 -> scalar (D=54, lanes 54..63 idle).
template <int D, int VEC>
__global__ __launch_bounds__(256) void k_agg(const float* __restrict__ h,
                                             const int* __restrict__ rowptr,
                                             const int* __restrict__ csr,
                                             float* __restrict__ agg, int n) {
    int w = threadIdx.x >> 6;
    int lane = threadIdx.x & 63;
    int i = blockIdx.x * 4 + w;
    if (i >= n) return;
    int b0 = rowptr[i], b1 = rowptr[i + 1];
    if constexpr (VEC == 4) {
        float4 acc = {0.f, 0.f, 0.f, 0.f};
        #pragma unroll 4
        for (int b = b0; b < b1; ++b) {
            int s = csr[b];
            float4 v = *reinterpret_cast<const float4*>(h + (size_t)s * D + lane * 4);
            acc.x += v.x; acc.y += v.y; acc.z += v.z; acc.w += v.w;
        }
        *reinterpret_cast<float4*>(agg + (size_t)i * D + lane * 4) = acc;
    } else if constexpr (VEC == 2) {
        float2 acc = {0.f, 0.f};
        #pragma unroll 4
        for (int b = b0; b < b1; ++b) {
            int s = csr[b];
            float2 v = *reinterpret_cast<const float2*>(h + (size_t)s * D + lane * 2);
            acc.x += v.x; acc.y += v.y;
        }
        *reinterpret_cast<float2*>(agg + (size_t)i * D + lane * 2) = acc;
    } else {
        if (lane < D) {
            float acc = 0.f;
            #pragma unroll 4
            for (int b = b0; b < b1; ++b) {
                int s = csr[b];
                acc += h[(size_t)s * D + lane];
            }
            agg[(size_t)i * D + lane] = acc;
        }
    }
}

// ---------------- fused GEMM: C = relu(A1@W1 + A2@W2 + bias) ----------------
// A1,A2: [N][KIN]  W1,W2: [KIN][DOUT]  C: [N][DOUT]
// BM=128 rows/block, BN=DOUT, BK=32. 256 threads, per-thread 8 rows x 16 cols.
template <int KIN, int DOUT, bool VEC4>
__global__ __launch_bounds__(256, 2) void k_gemm(const float* __restrict__ A1,
                                                 const float* __restrict__ A2,
                                                 const float* __restrict__ W1,
                                                 const float* __restrict__ W2,
                                                 const float* __restrict__ bias,
                                                 float* __restrict__ C, int N) {
    constexpr int BM = 128, BK = 32;
    constexpr int NJ = DOUT / 64;          // 2 or 4 col-chunks of float4 per thread
    constexpr int ASTR = BK + 4;           // 36 floats: pad to dodge bank conflicts
    __shared__ float As[BM * ASTR];
    __shared__ float Bs[BK * DOUT];

    int tid = threadIdx.x;
    int tr = tid >> 4;                     // 0..15
    int tc = tid & 15;                     // 0..15
    int m0 = blockIdx.x * BM;

    float4 acc[8][NJ];
    #pragma unroll
    for (int i = 0; i < 8; ++i)
        #pragma unroll
        for (int j = 0; j < NJ; ++j) acc[i][j] = {0.f, 0.f, 0.f, 0.f};

    const float* Asrc[2] = {A1, A2};
    const float* Wsrc[2] = {W1, W2};
    constexpr int KT = (KIN + BK - 1) / BK;

    for (int s = 0; s < 2; ++s) {
        const float* Ap = Asrc[s];
        const float* Wp = Wsrc[s];
        for (int kt = 0; kt < KT; ++kt) {
            int k0 = kt * BK;
            // ---- stage B tile [BK][DOUT], zero-fill k >= KIN ----
            {
                constexpr int NV = BK * DOUT / 4;  // float4 count
                #pragma unroll
                for (int it = 0; it < NV / 256; ++it) {
                    int v = it * 256 + tid;
                    int r = v / (DOUT / 4);
                    int c4 = v % (DOUT / 4);
                    int k = k0 + r;
                    float4 val = {0.f, 0.f, 0.f, 0.f};
                    if (k < KIN)
                        val = *reinterpret_cast<const float4*>(Wp + (size_t)k * DOUT + c4 * 4);
                    *reinterpret_cast<float4*>(&Bs[r * DOUT + c4 * 4]) = val;
                }
            }
            // ---- stage A tile [BM][BK] ----
            if constexpr (VEC4) {
                #pragma unroll
                for (int it = 0; it < 4; ++it) {   // 128*32/4/256
                    int v = it * 256 + tid;
                    int r = v >> 3;
                    int c4 = v & 7;
                    int m = m0 + r;
                    float4 val = {0.f, 0.f, 0.f, 0.f};
                    if (m < N)
                        val = *reinterpret_cast<const float4*>(Ap + (size_t)m * KIN + k0 + c4 * 4);
                    *reinterpret_cast<float4*>(&As[r * ASTR + c4 * 4]) = val;
                }
            } else {
                #pragma unroll
                for (int it = 0; it < 16; ++it) {  // 128*32/256 scalar
                    int v = it * 256 + tid;
                    int r = v >> 5;
                    int c = v & 31;
                    int m = m0 + r;
                    int k = k0 + c;
                    float val = 0.f;
                    if (m < N && k < KIN) val = Ap[(size_t)m * KIN + k];
                    As[r * ASTR + c] = val;
                }
            }
            __syncthreads();
            // ---- compute ----
            #pragma unroll
            for (int kk = 0; kk < BK; kk += 4) {
                float4 a[8];
                #pragma unroll
                for (int i = 0; i < 8; ++i)
                    a[i] = *reinterpret_cast<const float4*>(&As[(i * 16 + tr) * ASTR + kk]);
                #pragma unroll
                for (int kq = 0; kq < 4; ++kq) {
                    float4 bv[NJ];
                    #pragma unroll
                    for (int j = 0; j < NJ; ++j)
                        bv[j] = *reinterpret_cast<const float4*>(&Bs[(kk + kq) * DOUT + tc * 4 + 64 * j]);
                    #pragma unroll
                    for (int i = 0; i < 8; ++i) {
                        float av = (kq == 0) ? a[i].x : (kq == 1) ? a[i].y : (kq == 2) ? a[i].z : a[i].w;
                        #pragma unroll
                        for (int j = 0; j < NJ; ++j) {
                            acc[i][j].x = fmaf(av, bv[j].x, acc[i][j].x);
                            acc[i][j].y = fmaf(av, bv[j].y, acc[i][j].y);
                            acc[i][j].z = fmaf(av, bv[j].z, acc[i][j].z);
                            acc[i][j].w = fmaf(av, bv[j].w, acc[i][j].w);
                        }
                    }
                }
            }
            __syncthreads();
        }
    }
    // ---- epilogue: +bias, relu, store ----
    float4 bb[NJ];
    #pragma unroll
    for (int j = 0; j < NJ; ++j)
        bb[j] = *reinterpret_cast<const float4*>(bias + tc * 4 + 64 * j);
    #pragma unroll
    for (int i = 0; i < 8; ++i) {
        int m = m0 + i * 16 + tr;
        if (m < N) {
            #pragma unroll
            for (int j = 0; j < NJ; ++j) {
                float4 v;
                v.x = fmaxf(acc[i][j].x + bb[j].x, 0.f);
                v.y = fmaxf(acc[i][j].y + bb[j].y, 0.f);
                v.z = fmaxf(acc[i][j].z + bb[j].z, 0.f);
                v.w = fmaxf(acc[i][j].w + bb[j].w, 0.f);
                *reinterpret_cast<float4*>(C + (size_t)m * DOUT + tc * 4 + 64 * j) = v;
            }
        }
    }
}

// ---------------- global mean pool ----------------
// batch is sorted; each block scans a contiguous 256-node range, flushing a
// running sum to global atomics at each graph-id change.
__global__ void k_pool(const float* __restrict__ h3, const int* __restrict__ batch,
                       float* __restrict__ outsum, int* __restrict__ cnt, int N) {
    int r0 = blockIdx.x * 256;
    int r1 = min(r0 + 256, N);
    if (r0 >= N) return;
    int d = threadIdx.x;
    int cur = batch[r0];
    float s = 0.f;
    int c = 0;
    for (int i = r0; i < r1; ++i) {
        int g = batch[i];  // uniform across block
        if (g != cur) {
            atomicAdd(&outsum[cur * 256 + d], s);
            if (d == 0) atomicAdd(&cnt[cur], c);
            s = 0.f; c = 0; cur = g;
        }
        s += h3[(size_t)i * 256 + d];
        c++;
    }
    atomicAdd(&outsum[cur * 256 + d], s);
    if (d == 0) atomicAdd(&cnt[cur], c);
}

__global__ void k_div(float* __restrict__ out, const int* __restrict__ cnt, int total) {
    int idx = blockIdx.x * 256 + threadIdx.x;
    if (idx < total) {
        float c = fmaxf((float)cnt[idx >> 8], 1.0f);
        out[idx] = out[idx] / c;
    }
}

// ---------------------------------------------------------------------------
extern "C" void kernel_launch(void* const* d_in, const int* in_sizes, int n_in,
                              void* d_out, int out_size, void* d_ws, size_t ws_size,
                              hipStream_t stream) {
    const float* x   = (const float*)d_in[0];
    const int* ei    = (const int*)d_in[1];
    const int* batch = (const int*)d_in[2];
    const float* W1l = (const float*)d_in[3];
    const float* b1  = (const float*)d_in[4];
    const float* W1r = (const float*)d_in[5];
    const float* W2l = (const float*)d_in[6];
    const float* b2  = (const float*)d_in[7];
    const float* W2r = (const float*)d_in[8];
    const float* W3l = (const float*)d_in[9];
    const float* b3  = (const float*)d_in[10];
    const float* W3r = (const float*)d_in[11];

    const int N = in_sizes[0] / 54;
    const int E = in_sizes[1] / 2;
    const int* src = ei;
    const int* dst = ei + E;

    // workspace layout
    float* bufA = (float*)d_ws;                 // agg buffer, N*256
    float* buf1 = bufA + (size_t)N * 256;       // h1 then h3, N*256
    float* buf2 = buf1 + (size_t)N * 256;       // h2, N*256
    int* ip = (int*)(buf2 + (size_t)N * 256);
    int* cntdeg  = ip; ip += N;
    int* rowptr  = ip; ip += N + 1;
    int* wpos    = ip; ip += N;
    int* bsum    = ip; ip += 256;
    int* boff    = ip; ip += 256;
    int* cntpool = ip; ip += 128;
    int* csr     = ip;                           // E ints

    hipMemsetAsync(cntdeg, 0, (size_t)N * sizeof(int), stream);
    hipMemsetAsync(d_out, 0, (size_t)out_size * sizeof(float), stream);
    hipMemsetAsync(cntpool, 0, 128 * sizeof(int), stream);

    const int NB = (N + 255) / 256;
    const int EB = (E + 255) / 256;

    // CSR build
    k_count<<<EB, 256, 0, stream>>>(dst, cntdeg, E);
    k_bsum<<<NB, 256, 0, stream>>>(cntdeg, bsum, N);
    k_bscan<<<1, 256, 0, stream>>>(bsum, boff, NB);
    k_scan<<<NB, 256, 0, stream>>>(cntdeg, boff, rowptr, wpos, N, E);
    k_fill<<<EB, 256, 0, stream>>>(src, dst, wpos, csr, E);

    const int AGB = (N + 3) / 4;
    const int GGB = (N + 127) / 128;

    // layer 1: 54 -> 128
    k_agg<54, 1><<<AGB, 256, 0, stream>>>(x, rowptr, csr, bufA, N);
    k_gemm<54, 128, false><<<GGB, 256, 0, stream>>>(bufA, x, W1l, W1r, b1, buf1, N);
    // layer 2: 128 -> 256
    k_agg<128, 2><<<AGB, 256, 0, stream>>>(buf1, rowptr, csr, bufA, N);
    k_gemm<128, 256, true><<<GGB, 256, 0, stream>>>(bufA, buf1, W2l, W2r, b2, buf2, N);
    // layer 3: 256 -> 256
    k_agg<256, 4><<<AGB, 256, 0, stream>>>(buf2, rowptr, csr, bufA, N);
    k_gemm<256, 256, true><<<GGB, 256, 0, stream>>>(bufA, buf2, W3l, W3r, b3, buf1, N);

    // global mean pool
    k_pool<<<NB, 256, 0, stream>>>(buf1, batch, (float*)d_out, cntpool, N);
    k_div<<<(out_size + 255) / 256, 256, 0, stream>>>((float*)d_out, cntpool, out_size);
}

// Round 2
// 916.909 us; speedup vs baseline: 1.2310x; 1.2310x over previous
//
#include <hip/hip_runtime.h>

// ---------------------------------------------------------------------------
// GraphSAGE x3 (sum aggr) + global mean pool, fp32.
// Pipeline: build CSR over dst -> [agg -> fused GEMM relu(agg@Wl + h@Wr + b)] x3 -> pool
// ---------------------------------------------------------------------------

// ---------------- CSR build ----------------
__global__ void k_count(const int* __restrict__ dst, int* __restrict__ cnt, int E) {
    int e = blockIdx.x * 256 + threadIdx.x;
    if (e < E) atomicAdd(&cnt[dst[e]], 1);
}

__global__ void k_bsum(const int* __restrict__ cnt, int* __restrict__ bsum, int N) {
    __shared__ int sm[256];
    int i = blockIdx.x * 256 + threadIdx.x;
    sm[threadIdx.x] = (i < N) ? cnt[i] : 0;
    __syncthreads();
    for (int off = 128; off > 0; off >>= 1) {
        if (threadIdx.x < off) sm[threadIdx.x] += sm[threadIdx.x + off];
        __syncthreads();
    }
    if (threadIdx.x == 0) bsum[blockIdx.x] = sm[0];
}

// NB <= 256 (N=50000 -> NB=196)
__global__ void k_bscan(const int* __restrict__ bsum, int* __restrict__ boff, int NB) {
    __shared__ int sm[256];
    int t = threadIdx.x;
    int v = (t < NB) ? bsum[t] : 0;
    sm[t] = v;
    __syncthreads();
    for (int off = 1; off < 256; off <<= 1) {
        int add = (t >= off) ? sm[t - off] : 0;
        __syncthreads();
        sm[t] += add;
        __syncthreads();
    }
    if (t < NB) boff[t] = sm[t] - v;  // exclusive
}

__global__ void k_scan(const int* __restrict__ cnt, const int* __restrict__ boff,
                       int* __restrict__ rowptr, int* __restrict__ wpos, int N, int E) {
    __shared__ int sm[256];
    int t = threadIdx.x;
    int i = blockIdx.x * 256 + t;
    int v = (i < N) ? cnt[i] : 0;
    sm[t] = v;
    __syncthreads();
    for (int off = 1; off < 256; off <<= 1) {
        int add = (t >= off) ? sm[t - off] : 0;
        __syncthreads();
        sm[t] += add;
        __syncthreads();
    }
    int ex = sm[t] - v + boff[blockIdx.x];
    if (i < N) { rowptr[i] = ex; wpos[i] = ex; }
    if (i == 0) rowptr[N] = E;
}

__global__ void k_fill(const int* __restrict__ src, const int* __restrict__ dst,
                       int* __restrict__ wpos, int* __restrict__ csr, int E) {
    int e = blockIdx.x * 256 + threadIdx.x;
    if (e < E) {
        int p = atomicAdd(&wpos[dst[e]], 1);
        csr[p] = src[e];
    }
}

// ---------------- aggregation: agg[i] = sum_{e: dst==i} h[src[e]] ----------------
// 256-thread blocks = 4 waves, one wave per node.
template <int D, int VEC>
__global__ __launch_bounds__(256) void k_agg(const float* __restrict__ h,
                                             const int* __restrict__ rowptr,
                                             const int* __restrict__ csr,
                                             float* __restrict__ agg, int n) {
    int w = threadIdx.x >> 6;
    int lane = threadIdx.x & 63;
    int i = blockIdx.x * 4 + w;
    if (i >= n) return;
    int b0 = rowptr[i], b1 = rowptr[i + 1];
    if constexpr (VEC == 4) {
        float4 acc = {0.f, 0.f, 0.f, 0.f};
        #pragma unroll 4
        for (int b = b0; b < b1; ++b) {
            int s = csr[b];
            float4 v = *reinterpret_cast<const float4*>(h + (size_t)s * D + lane * 4);
            acc.x += v.x; acc.y += v.y; acc.z += v.z; acc.w += v.w;
        }
        *reinterpret_cast<float4*>(agg + (size_t)i * D + lane * 4) = acc;
    } else if constexpr (VEC == 2) {
        float2 acc = {0.f, 0.f};
        #pragma unroll 4
        for (int b = b0; b < b1; ++b) {
            int s = csr[b];
            float2 v = *reinterpret_cast<const float2*>(h + (size_t)s * D + lane * 2);
            acc.x += v.x; acc.y += v.y;
        }
        *reinterpret_cast<float2*>(agg + (size_t)i * D + lane * 2) = acc;
    } else {
        if (lane < D) {
            float acc = 0.f;
            #pragma unroll 4
            for (int b = b0; b < b1; ++b) {
                int s = csr[b];
                acc += h[(size_t)s * D + lane];
            }
            agg[(size_t)i * D + lane] = acc;
        }
    }
}

// ---------------- fused GEMM: C = relu(A1@W1 + A2@W2 + bias) ----------------
// A1,A2: [N][KIN]  W1,W2: [KIN][DOUT]  C: [N][DOUT]
// Block tile BM x BN (BN=128), BK=32. 256 threads as 16x16; per-thread
// (BM/16) rows x 8 cols -> acc = (BM/16)*2 float4 (<=64 floats, no spill).
// grid = (ceil(N/BM), DOUT/BN).
template <int KIN, int DOUT, int BM, bool VEC4>
__global__ __launch_bounds__(256, 3) void k_gemm(const float* __restrict__ A1,
                                                 const float* __restrict__ A2,
                                                 const float* __restrict__ W1,
                                                 const float* __restrict__ W2,
                                                 const float* __restrict__ bias,
                                                 float* __restrict__ C, int N) {
    constexpr int BK = 32, BN = 128;
    constexpr int MI = BM / 16;            // rows per thread (4 or 8)
    constexpr int NJ = BN / 64;            // 2 float4 col-chunks per thread
    constexpr int ASTR = BK + 4;           // pad to dodge bank conflicts
    __shared__ float As[BM * ASTR];
    __shared__ float Bs[BK * BN];

    int tid = threadIdx.x;
    int tr = tid >> 4;                     // 0..15
    int tc = tid & 15;                     // 0..15
    int m0 = blockIdx.x * BM;
    int n0 = blockIdx.y * BN;

    float4 acc[MI][NJ];
    #pragma unroll
    for (int i = 0; i < MI; ++i)
        #pragma unroll
        for (int j = 0; j < NJ; ++j) acc[i][j] = {0.f, 0.f, 0.f, 0.f};

    constexpr int KT = (KIN + BK - 1) / BK;

    #pragma unroll
    for (int s = 0; s < 2; ++s) {
        const float* __restrict__ Ap = (s == 0) ? A1 : A2;
        const float* __restrict__ Wp = (s == 0) ? W1 : W2;
        for (int kt = 0; kt < KT; ++kt) {
            int k0 = kt * BK;
            // ---- stage B tile [BK][BN], zero-fill k >= KIN ----
            #pragma unroll
            for (int it = 0; it < BK * BN / 4 / 256; ++it) {
                int v = it * 256 + tid;
                int r = v / (BN / 4);
                int c4 = v % (BN / 4);
                int k = k0 + r;
                float4 val = {0.f, 0.f, 0.f, 0.f};
                if (k < KIN)
                    val = *reinterpret_cast<const float4*>(Wp + (size_t)k * DOUT + n0 + c4 * 4);
                *reinterpret_cast<float4*>(&Bs[r * BN + c4 * 4]) = val;
            }
            // ---- stage A tile [BM][BK] ----
            if constexpr (VEC4) {
                #pragma unroll
                for (int it = 0; it < BM * BK / 4 / 256; ++it) {
                    int v = it * 256 + tid;
                    int r = v >> 3;
                    int c4 = v & 7;
                    int m = m0 + r;
                    float4 val = {0.f, 0.f, 0.f, 0.f};
                    if (m < N)
                        val = *reinterpret_cast<const float4*>(Ap + (size_t)m * KIN + k0 + c4 * 4);
                    *reinterpret_cast<float4*>(&As[r * ASTR + c4 * 4]) = val;
                }
            } else {
                #pragma unroll
                for (int it = 0; it < BM * BK / 256; ++it) {
                    int v = it * 256 + tid;
                    int r = v >> 5;
                    int c = v & 31;
                    int m = m0 + r;
                    int k = k0 + c;
                    float val = 0.f;
                    if (m < N && k < KIN) val = Ap[(size_t)m * KIN + k];
                    As[r * ASTR + c] = val;
                }
            }
            __syncthreads();
            // ---- compute ----
            #pragma unroll
            for (int kk = 0; kk < BK; kk += 4) {
                float4 a4[MI];
                #pragma unroll
                for (int i = 0; i < MI; ++i)
                    a4[i] = *reinterpret_cast<const float4*>(&As[(i * 16 + tr) * ASTR + kk]);
                #pragma unroll
                for (int kq = 0; kq < 4; ++kq) {
                    float4 bv[NJ];
                    #pragma unroll
                    for (int j = 0; j < NJ; ++j)
                        bv[j] = *reinterpret_cast<const float4*>(&Bs[(kk + kq) * BN + tc * 4 + 64 * j]);
                    #pragma unroll
                    for (int i = 0; i < MI; ++i) {
                        float av = (kq == 0) ? a4[i].x : (kq == 1) ? a4[i].y : (kq == 2) ? a4[i].z : a4[i].w;
                        #pragma unroll
                        for (int j = 0; j < NJ; ++j) {
                            acc[i][j].x = fmaf(av, bv[j].x, acc[i][j].x);
                            acc[i][j].y = fmaf(av, bv[j].y, acc[i][j].y);
                            acc[i][j].z = fmaf(av, bv[j].z, acc[i][j].z);
                            acc[i][j].w = fmaf(av, bv[j].w, acc[i][j].w);
                        }
                    }
                }
            }
            __syncthreads();
        }
    }
    // ---- epilogue: +bias, relu, store ----
    float4 bb[NJ];
    #pragma unroll
    for (int j = 0; j < NJ; ++j)
        bb[j] = *reinterpret_cast<const float4*>(bias + n0 + tc * 4 + 64 * j);
    #pragma unroll
    for (int i = 0; i < MI; ++i) {
        int m = m0 + i * 16 + tr;
        if (m < N) {
            #pragma unroll
            for (int j = 0; j < NJ; ++j) {
                float4 v;
                v.x = fmaxf(acc[i][j].x + bb[j].x, 0.f);
                v.y = fmaxf(acc[i][j].y + bb[j].y, 0.f);
                v.z = fmaxf(acc[i][j].z + bb[j].z, 0.f);
                v.w = fmaxf(acc[i][j].w + bb[j].w, 0.f);
                *reinterpret_cast<float4*>(C + (size_t)m * DOUT + n0 + tc * 4 + 64 * j) = v;
            }
        }
    }
}

// ---------------- global mean pool ----------------
__global__ void k_pool(const float* __restrict__ h3, const int* __restrict__ batch,
                       float* __restrict__ outsum, int* __restrict__ cnt, int N) {
    int r0 = blockIdx.x * 256;
    int r1 = min(r0 + 256, N);
    if (r0 >= N) return;
    int d = threadIdx.x;
    int cur = batch[r0];
    float s = 0.f;
    int c = 0;
    for (int i = r0; i < r1; ++i) {
        int g = batch[i];  // uniform across block
        if (g != cur) {
            atomicAdd(&outsum[cur * 256 + d], s);
            if (d == 0) atomicAdd(&cnt[cur], c);
            s = 0.f; c = 0; cur = g;
        }
        s += h3[(size_t)i * 256 + d];
        c++;
    }
    atomicAdd(&outsum[cur * 256 + d], s);
    if (d == 0) atomicAdd(&cnt[cur], c);
}

__global__ void k_div(float* __restrict__ out, const int* __restrict__ cnt, int total) {
    int idx = blockIdx.x * 256 + threadIdx.x;
    if (idx < total) {
        float c = fmaxf((float)cnt[idx >> 8], 1.0f);
        out[idx] = out[idx] / c;
    }
}

// ---------------------------------------------------------------------------
extern "C" void kernel_launch(void* const* d_in, const int* in_sizes, int n_in,
                              void* d_out, int out_size, void* d_ws, size_t ws_size,
                              hipStream_t stream) {
    const float* x   = (const float*)d_in[0];
    const int* ei    = (const int*)d_in[1];
    const int* batch = (const int*)d_in[2];
    const float* W1l = (const float*)d_in[3];
    const float* b1  = (const float*)d_in[4];
    const float* W1r = (const float*)d_in[5];
    const float* W2l = (const float*)d_in[6];
    const float* b2  = (const float*)d_in[7];
    const float* W2r = (const float*)d_in[8];
    const float* W3l = (const float*)d_in[9];
    const float* b3  = (const float*)d_in[10];
    const float* W3r = (const float*)d_in[11];

    const int N = in_sizes[0] / 54;
    const int E = in_sizes[1] / 2;
    const int* src = ei;
    const int* dst = ei + E;

    // workspace layout
    float* bufA = (float*)d_ws;                 // agg buffer, N*256
    float* buf1 = bufA + (size_t)N * 256;       // h1 then h3, N*256
    float* buf2 = buf1 + (size_t)N * 256;       // h2, N*256
    int* ip = (int*)(buf2 + (size_t)N * 256);
    int* cntdeg  = ip; ip += N;
    int* rowptr  = ip; ip += N + 1;
    int* wpos    = ip; ip += N;
    int* bsum    = ip; ip += 256;
    int* boff    = ip; ip += 256;
    int* cntpool = ip; ip += 128;
    int* csr     = ip;                           // E ints

    hipMemsetAsync(cntdeg, 0, (size_t)N * sizeof(int), stream);
    hipMemsetAsync(d_out, 0, (size_t)out_size * sizeof(float), stream);
    hipMemsetAsync(cntpool, 0, 128 * sizeof(int), stream);

    const int NB = (N + 255) / 256;
    const int EB = (E + 255) / 256;

    // CSR build
    k_count<<<EB, 256, 0, stream>>>(dst, cntdeg, E);
    k_bsum<<<NB, 256, 0, stream>>>(cntdeg, bsum, N);
    k_bscan<<<1, 256, 0, stream>>>(bsum, boff, NB);
    k_scan<<<NB, 256, 0, stream>>>(cntdeg, boff, rowptr, wpos, N, E);
    k_fill<<<EB, 256, 0, stream>>>(src, dst, wpos, csr, E);

    const int AGB = (N + 3) / 4;

    // layer 1: 54 -> 128   (BM=64, 1 col-block -> 782 blocks)
    k_agg<54, 1><<<AGB, 256, 0, stream>>>(x, rowptr, csr, bufA, N);
    {
        dim3 g((N + 63) / 64, 128 / 128);
        k_gemm<54, 128, 64, false><<<g, 256, 0, stream>>>(bufA, x, W1l, W1r, b1, buf1, N);
    }
    // layer 2: 128 -> 256  (BM=128, 2 col-blocks -> 782 blocks)
    k_agg<128, 2><<<AGB, 256, 0, stream>>>(buf1, rowptr, csr, bufA, N);
    {
        dim3 g((N + 127) / 128, 256 / 128);
        k_gemm<128, 256, 128, true><<<g, 256, 0, stream>>>(bufA, buf1, W2l, W2r, b2, buf2, N);
    }
    // layer 3: 256 -> 256
    k_agg<256, 4><<<AGB, 256, 0, stream>>>(buf2, rowptr, csr, bufA, N);
    {
        dim3 g((N + 127) / 128, 256 / 128);
        k_gemm<256, 256, 128, true><<<g, 256, 0, stream>>>(bufA, buf2, W3l, W3r, b3, buf1, N);
    }

    // global mean pool
    k_pool<<<NB, 256, 0, stream>>>(buf1, batch, (float*)d_out, cntpool, N);
    k_div<<<(out_size + 255) / 256, 256, 0, stream>>>((float*)d_out, cntpool, out_size);
}

// Round 3
// 776.937 us; speedup vs baseline: 1.4528x; 1.1802x over previous
//
#include <hip/hip_runtime.h>

// ---------------------------------------------------------------------------
// GraphSAGE x3 (sum aggr) + global mean pool, fp32.
// Pipeline: build CSR over dst -> [agg -> fused GEMM relu(agg@Wl + h@Wr + b)] x3 -> pool
// ---------------------------------------------------------------------------

// ---------------- CSR build ----------------
__global__ void k_count(const int* __restrict__ dst, int* __restrict__ cnt, int E) {
    int e = blockIdx.x * 256 + threadIdx.x;
    if (e < E) atomicAdd(&cnt[dst[e]], 1);
}

__global__ void k_bsum(const int* __restrict__ cnt, int* __restrict__ bsum, int N) {
    __shared__ int sm[256];
    int i = blockIdx.x * 256 + threadIdx.x;
    sm[threadIdx.x] = (i < N) ? cnt[i] : 0;
    __syncthreads();
    for (int off = 128; off > 0; off >>= 1) {
        if (threadIdx.x < off) sm[threadIdx.x] += sm[threadIdx.x + off];
        __syncthreads();
    }
    if (threadIdx.x == 0) bsum[blockIdx.x] = sm[0];
}

// NB <= 256 (N=50000 -> NB=196)
__global__ void k_bscan(const int* __restrict__ bsum, int* __restrict__ boff, int NB) {
    __shared__ int sm[256];
    int t = threadIdx.x;
    int v = (t < NB) ? bsum[t] : 0;
    sm[t] = v;
    __syncthreads();
    for (int off = 1; off < 256; off <<= 1) {
        int add = (t >= off) ? sm[t - off] : 0;
        __syncthreads();
        sm[t] += add;
        __syncthreads();
    }
    if (t < NB) boff[t] = sm[t] - v;  // exclusive
}

__global__ void k_scan(const int* __restrict__ cnt, const int* __restrict__ boff,
                       int* __restrict__ rowptr, int* __restrict__ wpos, int N, int E) {
    __shared__ int sm[256];
    int t = threadIdx.x;
    int i = blockIdx.x * 256 + t;
    int v = (i < N) ? cnt[i] : 0;
    sm[t] = v;
    __syncthreads();
    for (int off = 1; off < 256; off <<= 1) {
        int add = (t >= off) ? sm[t - off] : 0;
        __syncthreads();
        sm[t] += add;
        __syncthreads();
    }
    int ex = sm[t] - v + boff[blockIdx.x];
    if (i < N) { rowptr[i] = ex; wpos[i] = ex; }
    if (i == 0) rowptr[N] = E;
}

__global__ void k_fill(const int* __restrict__ src, const int* __restrict__ dst,
                       int* __restrict__ wpos, int* __restrict__ csr, int E) {
    int e = blockIdx.x * 256 + threadIdx.x;
    if (e < E) {
        int p = atomicAdd(&wpos[dst[e]], 1);
        csr[p] = src[e];
    }
}

// ---------------- aggregation: agg[i] = sum_{e: dst==i} h[src[e]] ----------------
// 256-thread blocks = 4 waves, one wave per node.
template <int D, int VEC>
__global__ __launch_bounds__(256) void k_agg(const float* __restrict__ h,
                                             const int* __restrict__ rowptr,
                                             const int* __restrict__ csr,
                                             float* __restrict__ agg, int n) {
    int w = threadIdx.x >> 6;
    int lane = threadIdx.x & 63;
    int i = blockIdx.x * 4 + w;
    if (i >= n) return;
    int b0 = rowptr[i], b1 = rowptr[i + 1];
    if constexpr (VEC == 4) {
        float4 acc = {0.f, 0.f, 0.f, 0.f};
        #pragma unroll 4
        for (int b = b0; b < b1; ++b) {
            int s = csr[b];
            float4 v = *reinterpret_cast<const float4*>(h + (size_t)s * D + lane * 4);
            acc.x += v.x; acc.y += v.y; acc.z += v.z; acc.w += v.w;
        }
        *reinterpret_cast<float4*>(agg + (size_t)i * D + lane * 4) = acc;
    } else if constexpr (VEC == 2) {
        float2 acc = {0.f, 0.f};
        #pragma unroll 4
        for (int b = b0; b < b1; ++b) {
            int s = csr[b];
            float2 v = *reinterpret_cast<const float2*>(h + (size_t)s * D + lane * 2);
            acc.x += v.x; acc.y += v.y;
        }
        *reinterpret_cast<float2*>(agg + (size_t)i * D + lane * 2) = acc;
    } else {
        if (lane < D) {
            float acc = 0.f;
            #pragma unroll 4
            for (int b = b0; b < b1; ++b) {
                int s = csr[b];
                acc += h[(size_t)s * D + lane];
            }
            agg[(size_t)i * D + lane] = acc;
        }
    }
}

// ---------------- fused GEMM: C = relu(A1@W1 + A2@W2 + bias) ----------------
// A1,A2: [N][KIN]  W1,W2: [KIN][DOUT]  C: [N][DOUT]
// Block tile BM=64 x BN=DOUT (full width -> each A panel fetched exactly once).
// BK=32. 256 threads as 16x16; per-thread 4 rows x (DOUT/16) cols.
// acc = 4*(DOUT/64) float4 = 64 floats at DOUT=256 -> fits in VGPRs, NO
// launch_bounds min-waves (a min-occupancy hint made the allocator spill).
template <int KIN, int DOUT, bool VEC4>
__global__ __launch_bounds__(256) void k_gemm(const float* __restrict__ A1,
                                              const float* __restrict__ A2,
                                              const float* __restrict__ W1,
                                              const float* __restrict__ W2,
                                              const float* __restrict__ bias,
                                              float* __restrict__ C, int N) {
    constexpr int BK = 32, BM = 64, BN = DOUT;
    constexpr int MI = BM / 16;            // 4 rows per thread
    constexpr int NJ = BN / 64;            // float4 col-chunks per thread (2 or 4)
    constexpr int ASTR = BK + 4;           // pad to dodge bank conflicts
    __shared__ float As[BM * ASTR];
    __shared__ float Bs[BK * BN];

    int tid = threadIdx.x;
    int tr = tid >> 4;                     // 0..15
    int tc = tid & 15;                     // 0..15
    int m0 = blockIdx.x * BM;

    float4 acc[MI][NJ];
    #pragma unroll
    for (int i = 0; i < MI; ++i)
        #pragma unroll
        for (int j = 0; j < NJ; ++j) acc[i][j] = {0.f, 0.f, 0.f, 0.f};

    constexpr int KT = (KIN + BK - 1) / BK;

    #pragma unroll
    for (int s = 0; s < 2; ++s) {
        const float* __restrict__ Ap = (s == 0) ? A1 : A2;
        const float* __restrict__ Wp = (s == 0) ? W1 : W2;
        for (int kt = 0; kt < KT; ++kt) {
            int k0 = kt * BK;
            // ---- stage B tile [BK][BN], zero-fill k >= KIN ----
            #pragma unroll
            for (int it = 0; it < BK * BN / 4 / 256; ++it) {
                int v = it * 256 + tid;
                int r = v / (BN / 4);
                int c4 = v % (BN / 4);
                int k = k0 + r;
                float4 val = {0.f, 0.f, 0.f, 0.f};
                if (k < KIN)
                    val = *reinterpret_cast<const float4*>(Wp + (size_t)k * DOUT + c4 * 4);
                *reinterpret_cast<float4*>(&Bs[r * BN + c4 * 4]) = val;
            }
            // ---- stage A tile [BM][BK] ----
            if constexpr (VEC4) {
                #pragma unroll
                for (int it = 0; it < BM * BK / 4 / 256; ++it) {
                    int v = it * 256 + tid;
                    int r = v >> 3;
                    int c4 = v & 7;
                    int m = m0 + r;
                    float4 val = {0.f, 0.f, 0.f, 0.f};
                    if (m < N)
                        val = *reinterpret_cast<const float4*>(Ap + (size_t)m * KIN + k0 + c4 * 4);
                    *reinterpret_cast<float4*>(&As[r * ASTR + c4 * 4]) = val;
                }
            } else {
                #pragma unroll
                for (int it = 0; it < BM * BK / 256; ++it) {
                    int v = it * 256 + tid;
                    int r = v >> 5;
                    int c = v & 31;
                    int m = m0 + r;
                    int k = k0 + c;
                    float val = 0.f;
                    if (m < N && k < KIN) val = Ap[(size_t)m * KIN + k];
                    As[r * ASTR + c] = val;
                }
            }
            __syncthreads();
            // ---- compute ----
            #pragma unroll
            for (int kk = 0; kk < BK; kk += 4) {
                float4 a4[MI];
                #pragma unroll
                for (int i = 0; i < MI; ++i)
                    a4[i] = *reinterpret_cast<const float4*>(&As[(i * 16 + tr) * ASTR + kk]);
                #pragma unroll
                for (int kq = 0; kq < 4; ++kq) {
                    float4 bv[NJ];
                    #pragma unroll
                    for (int j = 0; j < NJ; ++j)
                        bv[j] = *reinterpret_cast<const float4*>(&Bs[(kk + kq) * BN + tc * 4 + 64 * j]);
                    #pragma unroll
                    for (int i = 0; i < MI; ++i) {
                        float av = (kq == 0) ? a4[i].x : (kq == 1) ? a4[i].y : (kq == 2) ? a4[i].z : a4[i].w;
                        #pragma unroll
                        for (int j = 0; j < NJ; ++j) {
                            acc[i][j].x = fmaf(av, bv[j].x, acc[i][j].x);
                            acc[i][j].y = fmaf(av, bv[j].y, acc[i][j].y);
                            acc[i][j].z = fmaf(av, bv[j].z, acc[i][j].z);
                            acc[i][j].w = fmaf(av, bv[j].w, acc[i][j].w);
                        }
                    }
                }
            }
            __syncthreads();
        }
    }
    // ---- epilogue: +bias, relu, store ----
    float4 bb[NJ];
    #pragma unroll
    for (int j = 0; j < NJ; ++j)
        bb[j] = *reinterpret_cast<const float4*>(bias + tc * 4 + 64 * j);
    #pragma unroll
    for (int i = 0; i < MI; ++i) {
        int m = m0 + i * 16 + tr;
        if (m < N) {
            #pragma unroll
            for (int j = 0; j < NJ; ++j) {
                float4 v;
                v.x = fmaxf(acc[i][j].x + bb[j].x, 0.f);
                v.y = fmaxf(acc[i][j].y + bb[j].y, 0.f);
                v.z = fmaxf(acc[i][j].z + bb[j].z, 0.f);
                v.w = fmaxf(acc[i][j].w + bb[j].w, 0.f);
                *reinterpret_cast<float4*>(C + (size_t)m * DOUT + tc * 4 + 64 * j) = v;
            }
        }
    }
}

// ---------------- global mean pool ----------------
__global__ void k_pool(const float* __restrict__ h3, const int* __restrict__ batch,
                       float* __restrict__ outsum, int* __restrict__ cnt, int N) {
    int r0 = blockIdx.x * 256;
    int r1 = min(r0 + 256, N);
    if (r0 >= N) return;
    int d = threadIdx.x;
    int cur = batch[r0];
    float s = 0.f;
    int c = 0;
    for (int i = r0; i < r1; ++i) {
        int g = batch[i];  // uniform across block
        if (g != cur) {
            atomicAdd(&outsum[cur * 256 + d], s);
            if (d == 0) atomicAdd(&cnt[cur], c);
            s = 0.f; c = 0; cur = g;
        }
        s += h3[(size_t)i * 256 + d];
        c++;
    }
    atomicAdd(&outsum[cur * 256 + d], s);
    if (d == 0) atomicAdd(&cnt[cur], c);
}

__global__ void k_div(float* __restrict__ out, const int* __restrict__ cnt, int total) {
    int idx = blockIdx.x * 256 + threadIdx.x;
    if (idx < total) {
        float c = fmaxf((float)cnt[idx >> 8], 1.0f);
        out[idx] = out[idx] / c;
    }
}

// ---------------------------------------------------------------------------
extern "C" void kernel_launch(void* const* d_in, const int* in_sizes, int n_in,
                              void* d_out, int out_size, void* d_ws, size_t ws_size,
                              hipStream_t stream) {
    const float* x   = (const float*)d_in[0];
    const int* ei    = (const int*)d_in[1];
    const int* batch = (const int*)d_in[2];
    const float* W1l = (const float*)d_in[3];
    const float* b1  = (const float*)d_in[4];
    const float* W1r = (const float*)d_in[5];
    const float* W2l = (const float*)d_in[6];
    const float* b2  = (const float*)d_in[7];
    const float* W2r = (const float*)d_in[8];
    const float* W3l = (const float*)d_in[9];
    const float* b3  = (const float*)d_in[10];
    const float* W3r = (const float*)d_in[11];

    const int N = in_sizes[0] / 54;
    const int E = in_sizes[1] / 2;
    const int* src = ei;
    const int* dst = ei + E;

    // workspace layout
    float* bufA = (float*)d_ws;                 // agg buffer, N*256
    float* buf1 = bufA + (size_t)N * 256;       // h1 then h3, N*256
    float* buf2 = buf1 + (size_t)N * 256;       // h2, N*256
    int* ip = (int*)(buf2 + (size_t)N * 256);
    int* cntdeg  = ip; ip += N;
    int* rowptr  = ip; ip += N + 1;
    int* wpos    = ip; ip += N;
    int* bsum    = ip; ip += 256;
    int* boff    = ip; ip += 256;
    int* cntpool = ip; ip += 128;
    int* csr     = ip;                           // E ints

    hipMemsetAsync(cntdeg, 0, (size_t)N * sizeof(int), stream);
    hipMemsetAsync(d_out, 0, (size_t)out_size * sizeof(float), stream);
    hipMemsetAsync(cntpool, 0, 128 * sizeof(int), stream);

    const int NB = (N + 255) / 256;
    const int EB = (E + 255) / 256;

    // CSR build
    k_count<<<EB, 256, 0, stream>>>(dst, cntdeg, E);
    k_bsum<<<NB, 256, 0, stream>>>(cntdeg, bsum, N);
    k_bscan<<<1, 256, 0, stream>>>(bsum, boff, NB);
    k_scan<<<NB, 256, 0, stream>>>(cntdeg, boff, rowptr, wpos, N, E);
    k_fill<<<EB, 256, 0, stream>>>(src, dst, wpos, csr, E);

    const int AGB = (N + 3) / 4;
    const int GGB = (N + 63) / 64;   // BM=64

    // layer 1: 54 -> 128
    k_agg<54, 1><<<AGB, 256, 0, stream>>>(x, rowptr, csr, bufA, N);
    k_gemm<54, 128, false><<<GGB, 256, 0, stream>>>(bufA, x, W1l, W1r, b1, buf1, N);
    // layer 2: 128 -> 256
    k_agg<128, 2><<<AGB, 256, 0, stream>>>(buf1, rowptr, csr, bufA, N);
    k_gemm<128, 256, true><<<GGB, 256, 0, stream>>>(bufA, buf1, W2l, W2r, b2, buf2, N);
    // layer 3: 256 -> 256
    k_agg<256, 4><<<AGB, 256, 0, stream>>>(buf2, rowptr, csr, bufA, N);
    k_gemm<256, 256, true><<<GGB, 256, 0, stream>>>(bufA, buf2, W3l, W3r, b3, buf1, N);

    // global mean pool
    k_pool<<<NB, 256, 0, stream>>>(buf1, batch, (float*)d_out, cntpool, N);
    k_div<<<(out_size + 255) / 256, 256, 0, stream>>>((float*)d_out, cntpool, out_size);
}

// Round 4
// 409.202 us; speedup vs baseline: 2.7584x; 1.8987x over previous
//
#include <hip/hip_runtime.h>

// ---------------------------------------------------------------------------
// GraphSAGE x3 (sum aggr) + global mean pool.
// bf16 storage + MFMA 16x16x32 GEMMs (fp32 accum). Threshold is bf16-scaled.
// Pipeline: prep (bf16 cvt + weight transpose) -> CSR -> [agg -> MFMA GEMM] x3 -> pool
// ---------------------------------------------------------------------------

typedef unsigned short u16;
typedef __attribute__((ext_vector_type(8))) short bf16x8;
typedef __attribute__((ext_vector_type(4))) float f32x4;

__device__ __forceinline__ u16 f2b(float f) {
    union { float f; unsigned u; } v; v.f = f;
    unsigned u = v.u;
    return (u16)((u + 0x7FFF + ((u >> 16) & 1)) >> 16);   // RNE
}
__device__ __forceinline__ float b2f(u16 h) {
    union { unsigned u; float f; } v; v.u = ((unsigned)h) << 16;
    return v.f;
}

// ---------------- prep: x -> bf16, weights -> bf16 transposed [D][KP] ----------------
// segments: xb (N*54) | wt1l,wt1r [128][64] (K=54) | wt2l,wt2r [256][128] | wt3l,wt3r [256][256]
__global__ void k_prep(const float* __restrict__ x,
                       const float* __restrict__ W1l, const float* __restrict__ W1r,
                       const float* __restrict__ W2l, const float* __restrict__ W2r,
                       const float* __restrict__ W3l, const float* __restrict__ W3r,
                       u16* __restrict__ xb,
                       u16* __restrict__ wt1l, u16* __restrict__ wt1r,
                       u16* __restrict__ wt2l, u16* __restrict__ wt2r,
                       u16* __restrict__ wt3l, u16* __restrict__ wt3r, int N) {
    long idx = (long)blockIdx.x * 256 + threadIdx.x;
    long s0 = (long)N * 54;
    if (idx < s0) { xb[idx] = f2b(x[idx]); return; }
    idx -= s0;
    // wt1: D=128, KP=64, K=54
    if (idx < 2 * 128 * 64) {
        u16* o = (idx < 128 * 64) ? wt1l : wt1r;
        const float* w = (idx < 128 * 64) ? W1l : W1r;
        long loc = idx % (128 * 64);
        int d = (int)(loc >> 6), k = (int)(loc & 63);
        o[loc] = (k < 54) ? f2b(w[(long)k * 128 + d]) : 0;
        return;
    }
    idx -= 2 * 128 * 64;
    // wt2: D=256, KP=K=128
    if (idx < 2 * 256 * 128) {
        u16* o = (idx < 256 * 128) ? wt2l : wt2r;
        const float* w = (idx < 256 * 128) ? W2l : W2r;
        long loc = idx % (256 * 128);
        int d = (int)(loc >> 7), k = (int)(loc & 127);
        o[loc] = f2b(w[(long)k * 256 + d]);
        return;
    }
    idx -= 2 * 256 * 128;
    // wt3: D=256, KP=K=256
    if (idx < 2 * 256 * 256) {
        u16* o = (idx < 256 * 256) ? wt3l : wt3r;
        const float* w = (idx < 256 * 256) ? W3l : W3r;
        long loc = idx % (256 * 256);
        int d = (int)(loc >> 8), k = (int)(loc & 255);
        o[loc] = f2b(w[(long)k * 256 + d]);
    }
}

// ---------------- CSR build ----------------
__global__ void k_count(const int* __restrict__ dst, int* __restrict__ cnt, int E) {
    int e = blockIdx.x * 256 + threadIdx.x;
    if (e < E) atomicAdd(&cnt[dst[e]], 1);
}

__global__ void k_bsum(const int* __restrict__ cnt, int* __restrict__ bsum, int N) {
    __shared__ int sm[256];
    int i = blockIdx.x * 256 + threadIdx.x;
    sm[threadIdx.x] = (i < N) ? cnt[i] : 0;
    __syncthreads();
    for (int off = 128; off > 0; off >>= 1) {
        if (threadIdx.x < off) sm[threadIdx.x] += sm[threadIdx.x + off];
        __syncthreads();
    }
    if (threadIdx.x == 0) bsum[blockIdx.x] = sm[0];
}

__global__ void k_bscan(const int* __restrict__ bsum, int* __restrict__ boff, int NB) {
    __shared__ int sm[256];
    int t = threadIdx.x;
    int v = (t < NB) ? bsum[t] : 0;
    sm[t] = v;
    __syncthreads();
    for (int off = 1; off < 256; off <<= 1) {
        int add = (t >= off) ? sm[t - off] : 0;
        __syncthreads();
        sm[t] += add;
        __syncthreads();
    }
    if (t < NB) boff[t] = sm[t] - v;  // exclusive
}

__global__ void k_scan(const int* __restrict__ cnt, const int* __restrict__ boff,
                       int* __restrict__ rowptr, int* __restrict__ wpos, int N, int E) {
    __shared__ int sm[256];
    int t = threadIdx.x;
    int i = blockIdx.x * 256 + t;
    int v = (i < N) ? cnt[i] : 0;
    sm[t] = v;
    __syncthreads();
    for (int off = 1; off < 256; off <<= 1) {
        int add = (t >= off) ? sm[t - off] : 0;
        __syncthreads();
        sm[t] += add;
        __syncthreads();
    }
    int ex = sm[t] - v + boff[blockIdx.x];
    if (i < N) { rowptr[i] = ex; wpos[i] = ex; }
    if (i == 0) rowptr[N] = E;
}

__global__ void k_fill(const int* __restrict__ src, const int* __restrict__ dst,
                       int* __restrict__ wpos, int* __restrict__ csr, int E) {
    int e = blockIdx.x * 256 + threadIdx.x;
    if (e < E) {
        int p = atomicAdd(&wpos[dst[e]], 1);
        csr[p] = src[e];
    }
}

// ---------------- aggregation (bf16 in/out, fp32 accum) ----------------
// one wave per node; VEC = bf16 elems per lane (4 / 2 / 1)
template <int D, int VEC>
__global__ __launch_bounds__(256) void k_agg(const u16* __restrict__ h,
                                             const int* __restrict__ rowptr,
                                             const int* __restrict__ csr,
                                             u16* __restrict__ agg, int n) {
    int w = threadIdx.x >> 6;
    int lane = threadIdx.x & 63;
    int i = blockIdx.x * 4 + w;
    if (i >= n) return;
    int b0 = rowptr[i], b1 = rowptr[i + 1];
    if constexpr (VEC == 4) {
        float a0 = 0.f, a1 = 0.f, a2 = 0.f, a3 = 0.f;
        #pragma unroll 4
        for (int b = b0; b < b1; ++b) {
            int s = csr[b];
            ushort4 v = *reinterpret_cast<const ushort4*>(h + (size_t)s * D + lane * 4);
            a0 += b2f(v.x); a1 += b2f(v.y); a2 += b2f(v.z); a3 += b2f(v.w);
        }
        ushort4 o; o.x = f2b(a0); o.y = f2b(a1); o.z = f2b(a2); o.w = f2b(a3);
        *reinterpret_cast<ushort4*>(agg + (size_t)i * D + lane * 4) = o;
    } else if constexpr (VEC == 2) {
        float a0 = 0.f, a1 = 0.f;
        #pragma unroll 4
        for (int b = b0; b < b1; ++b) {
            int s = csr[b];
            ushort2 v = *reinterpret_cast<const ushort2*>(h + (size_t)s * D + lane * 2);
            a0 += b2f(v.x); a1 += b2f(v.y);
        }
        ushort2 o; o.x = f2b(a0); o.y = f2b(a1);
        *reinterpret_cast<ushort2*>(agg + (size_t)i * D + lane * 2) = o;
    } else {
        if (lane < D) {
            float a0 = 0.f;
            #pragma unroll 4
            for (int b = b0; b < b1; ++b) {
                int s = csr[b];
                a0 += b2f(h[(size_t)s * D + lane]);
            }
            agg[(size_t)i * D + lane] = f2b(a0);
        }
    }
}

// ---------------- MFMA GEMM: C = relu(A1@W1 + A2@W2 + bias), bf16 in/out ----------------
// A1,A2: [N][KA] bf16 row-major. Wt1,Wt2: [DOUT][KW] bf16 (transposed, zero-padded
// KA..KW). bias fp32. Tile BM=128 x BN=128, BK=32; 4 waves 2x2; per wave 4x4
// frags of mfma_f32_16x16x32_bf16. Operands: a = Wt-frag (W^T), b = X-frag (X^T)
// -> D[feat][node]; lane holds 4 consecutive feats of one node (m89 layout).
template <int KA, int KW, int DOUT, bool A16>
__global__ __launch_bounds__(256) void k_mgemm(const u16* __restrict__ A1,
                                               const u16* __restrict__ A2,
                                               const u16* __restrict__ Wt1,
                                               const u16* __restrict__ Wt2,
                                               const float* __restrict__ bias,
                                               u16* __restrict__ C, int N) {
    constexpr int BM = 128, BKP = 40;      // LDS rows padded to 80B -> 2-way only
    __shared__ u16 As[BM * BKP];           // X tile   [128 nodes][32 k]
    __shared__ u16 Bs[BM * BKP];           // Wt tile  [128 feats][32 k]

    const int tid = threadIdx.x;
    const int w = tid >> 6, l = tid & 63;
    const int wr = w >> 1, wc = w & 1;     // wave grid 2x2: wr = node dir, wc = feat dir
    const int lo = l & 15, hi = l >> 4;
    const int m0 = blockIdx.x * BM;
    const int n0 = blockIdx.y * 128;

    f32x4 acc[4][4];
    #pragma unroll
    for (int i = 0; i < 4; ++i)
        #pragma unroll
        for (int j = 0; j < 4; ++j) acc[i][j] = {0.f, 0.f, 0.f, 0.f};

    constexpr int KT = KW / 32;

    #pragma unroll
    for (int s = 0; s < 2; ++s) {
        const u16* __restrict__ Ap = s ? A2 : A1;
        const u16* __restrict__ Wp = s ? Wt2 : Wt1;
        for (int kt = 0; kt < KT; ++kt) {
            const int k0 = kt * 32;
            // stage Wt tile: 128 rows x 4 chunks of 16B
            #pragma unroll
            for (int it = 0; it < 2; ++it) {
                int v = it * 256 + tid;
                int r = v >> 2, c = v & 3;
                uint4 val = *reinterpret_cast<const uint4*>(Wp + (size_t)(n0 + r) * KW + k0 + c * 8);
                *reinterpret_cast<uint4*>(&Bs[r * BKP + c * 8]) = val;
            }
            // stage X tile
            if constexpr (A16) {
                #pragma unroll
                for (int it = 0; it < 2; ++it) {
                    int v = it * 256 + tid;
                    int r = v >> 2, c = v & 3;
                    int m = m0 + r;
                    uint4 val = {0u, 0u, 0u, 0u};
                    if (m < N) val = *reinterpret_cast<const uint4*>(Ap + (size_t)m * KA + k0 + c * 8);
                    *reinterpret_cast<uint4*>(&As[r * BKP + c * 8]) = val;
                }
            } else {
                // KA=54: 4B granularity (rows are 108B), zero-fill k >= KA
                #pragma unroll
                for (int it = 0; it < 8; ++it) {
                    int v = it * 256 + tid;
                    int r = v >> 4, c = v & 15;
                    int m = m0 + r;
                    int k = k0 + c * 2;
                    unsigned val = 0;
                    if (m < N && k < KA)
                        val = *reinterpret_cast<const unsigned*>(Ap + (size_t)m * KA + k);
                    *reinterpret_cast<unsigned*>(&As[r * BKP + c * 2]) = val;
                }
            }
            __syncthreads();
            bf16x8 af[4], bf[4];
            #pragma unroll
            for (int f = 0; f < 4; ++f) {
                af[f] = *reinterpret_cast<const bf16x8*>(&Bs[(wc * 64 + f * 16 + lo) * BKP + hi * 8]);
                bf[f] = *reinterpret_cast<const bf16x8*>(&As[(wr * 64 + f * 16 + lo) * BKP + hi * 8]);
            }
            #pragma unroll
            for (int fm = 0; fm < 4; ++fm)
                #pragma unroll
                for (int fn = 0; fn < 4; ++fn)
                    acc[fm][fn] = __builtin_amdgcn_mfma_f32_16x16x32_bf16(af[fn], bf[fm], acc[fm][fn], 0, 0, 0);
            __syncthreads();
        }
    }
    // epilogue: D[feat=(hi*4+r)+16*fn+64*wc][node=lo+16*fm+64*wr]
    #pragma unroll
    for (int fm = 0; fm < 4; ++fm) {
        int node = m0 + wr * 64 + fm * 16 + lo;
        if (node < N) {
            #pragma unroll
            for (int fn = 0; fn < 4; ++fn) {
                int fb = n0 + wc * 64 + fn * 16 + hi * 4;
                float4 bv = *reinterpret_cast<const float4*>(bias + fb);
                ushort4 o;
                o.x = f2b(fmaxf(acc[fm][fn][0] + bv.x, 0.f));
                o.y = f2b(fmaxf(acc[fm][fn][1] + bv.y, 0.f));
                o.z = f2b(fmaxf(acc[fm][fn][2] + bv.z, 0.f));
                o.w = f2b(fmaxf(acc[fm][fn][3] + bv.w, 0.f));
                *reinterpret_cast<ushort4*>(C + (size_t)node * DOUT + fb) = o;
            }
        }
    }
}

// ---------------- global mean pool (bf16 in, fp32 out) ----------------
__global__ void k_pool(const u16* __restrict__ h3, const int* __restrict__ batch,
                       float* __restrict__ outsum, int* __restrict__ cnt, int N) {
    int r0 = blockIdx.x * 256;
    int r1 = min(r0 + 256, N);
    if (r0 >= N) return;
    int d = threadIdx.x;
    int cur = batch[r0];
    float s = 0.f;
    int c = 0;
    for (int i = r0; i < r1; ++i) {
        int g = batch[i];  // uniform across block
        if (g != cur) {
            atomicAdd(&outsum[cur * 256 + d], s);
            if (d == 0) atomicAdd(&cnt[cur], c);
            s = 0.f; c = 0; cur = g;
        }
        s += b2f(h3[(size_t)i * 256 + d]);
        c++;
    }
    atomicAdd(&outsum[cur * 256 + d], s);
    if (d == 0) atomicAdd(&cnt[cur], c);
}

__global__ void k_div(float* __restrict__ out, const int* __restrict__ cnt, int total) {
    int idx = blockIdx.x * 256 + threadIdx.x;
    if (idx < total) {
        float c = fmaxf((float)cnt[idx >> 8], 1.0f);
        out[idx] = out[idx] / c;
    }
}

// ---------------------------------------------------------------------------
extern "C" void kernel_launch(void* const* d_in, const int* in_sizes, int n_in,
                              void* d_out, int out_size, void* d_ws, size_t ws_size,
                              hipStream_t stream) {
    const float* x   = (const float*)d_in[0];
    const int* ei    = (const int*)d_in[1];
    const int* batch = (const int*)d_in[2];
    const float* W1l = (const float*)d_in[3];
    const float* b1  = (const float*)d_in[4];
    const float* W1r = (const float*)d_in[5];
    const float* W2l = (const float*)d_in[6];
    const float* b2  = (const float*)d_in[7];
    const float* W2r = (const float*)d_in[8];
    const float* W3l = (const float*)d_in[9];
    const float* b3  = (const float*)d_in[10];
    const float* W3r = (const float*)d_in[11];

    const int N = in_sizes[0] / 54;
    const int E = in_sizes[1] / 2;
    const int* src = ei;
    const int* dst = ei + E;

    // workspace layout (bf16 = u16)
    u16* xb   = (u16*)d_ws;                       // N*54
    u16* bufA = xb + (size_t)N * 54;              // agg out, N*256 max
    u16* buf1 = bufA + (size_t)N * 256;           // h1 / h3
    u16* buf2 = buf1 + (size_t)N * 256;           // h2
    u16* wt1l = buf2 + (size_t)N * 256;           // [128][64]
    u16* wt1r = wt1l + 128 * 64;
    u16* wt2l = wt1r + 128 * 64;                  // [256][128]
    u16* wt2r = wt2l + 256 * 128;
    u16* wt3l = wt2r + 256 * 128;                 // [256][256]
    u16* wt3r = wt3l + 256 * 256;
    int* ip = (int*)(wt3r + 256 * 256);
    int* cntdeg  = ip; ip += N;
    int* rowptr  = ip; ip += N + 1;
    int* wpos    = ip; ip += N + 1;
    int* bsum    = ip; ip += 256;
    int* boff    = ip; ip += 256;
    int* cntpool = ip; ip += 128;
    int* csr     = ip;                            // E ints

    hipMemsetAsync(cntdeg, 0, (size_t)N * sizeof(int), stream);
    hipMemsetAsync(d_out, 0, (size_t)out_size * sizeof(float), stream);
    hipMemsetAsync(cntpool, 0, 128 * sizeof(int), stream);

    const int NB = (N + 255) / 256;
    const int EB = (E + 255) / 256;

    // prep: bf16 conversions + weight transposes
    {
        long total = (long)N * 54 + 2L * 128 * 64 + 2L * 256 * 128 + 2L * 256 * 256;
        int g = (int)((total + 255) / 256);
        k_prep<<<g, 256, 0, stream>>>(x, W1l, W1r, W2l, W2r, W3l, W3r,
                                      xb, wt1l, wt1r, wt2l, wt2r, wt3l, wt3r, N);
    }

    // CSR build
    k_count<<<EB, 256, 0, stream>>>(dst, cntdeg, E);
    k_bsum<<<NB, 256, 0, stream>>>(cntdeg, bsum, N);
    k_bscan<<<1, 256, 0, stream>>>(bsum, boff, NB);
    k_scan<<<NB, 256, 0, stream>>>(cntdeg, boff, rowptr, wpos, N, E);
    k_fill<<<EB, 256, 0, stream>>>(src, dst, wpos, csr, E);

    const int AGB = (N + 3) / 4;
    const int GX = (N + 127) / 128;

    // layer 1: 54 -> 128
    k_agg<54, 1><<<AGB, 256, 0, stream>>>(xb, rowptr, csr, bufA, N);
    {
        dim3 g(GX, 1);
        k_mgemm<54, 64, 128, false><<<g, 256, 0, stream>>>(bufA, xb, wt1l, wt1r, b1, buf1, N);
    }
    // layer 2: 128 -> 256
    k_agg<128, 2><<<AGB, 256, 0, stream>>>(buf1, rowptr, csr, bufA, N);
    {
        dim3 g(GX, 2);
        k_mgemm<128, 128, 256, true><<<g, 256, 0, stream>>>(bufA, buf1, wt2l, wt2r, b2, buf2, N);
    }
    // layer 3: 256 -> 256
    k_agg<256, 4><<<AGB, 256, 0, stream>>>(buf2, rowptr, csr, bufA, N);
    {
        dim3 g(GX, 2);
        k_mgemm<256, 256, 256, true><<<g, 256, 0, stream>>>(bufA, buf2, wt3l, wt3r, b3, buf1, N);
    }

    // global mean pool
    k_pool<<<NB, 256, 0, stream>>>(buf1, batch, (float*)d_out, cntpool, N);
    k_div<<<(out_size + 255) / 256, 256, 0, stream>>>((float*)d_out, cntpool, out_size);
}

// Round 5
// 358.709 us; speedup vs baseline: 3.1466x; 1.1408x over previous
//
#include <hip/hip_runtime.h>

// ---------------------------------------------------------------------------
// GraphSAGE x3 (sum aggr) + global mean pool.
// bf16 storage + MFMA 16x16x32 GEMMs (fp32 accum). Threshold is bf16-scaled.
// Pipeline: prep (bf16 cvt + weight transpose) -> CSR -> [agg -> MFMA GEMM] x3 -> pool
// ---------------------------------------------------------------------------

typedef unsigned short u16;
typedef __attribute__((ext_vector_type(8))) short bf16x8;
typedef __attribute__((ext_vector_type(4))) float f32x4;

__device__ __forceinline__ u16 f2b(float f) {
    union { float f; unsigned u; } v; v.f = f;
    unsigned u = v.u;
    return (u16)((u + 0x7FFF + ((u >> 16) & 1)) >> 16);   // RNE
}
__device__ __forceinline__ float b2f(u16 h) {
    union { unsigned u; float f; } v; v.u = ((unsigned)h) << 16;
    return v.f;
}

// ---------------- prep: x -> bf16, weights -> bf16 transposed [D][KP] ----------------
__global__ void k_prep(const float* __restrict__ x,
                       const float* __restrict__ W1l, const float* __restrict__ W1r,
                       const float* __restrict__ W2l, const float* __restrict__ W2r,
                       const float* __restrict__ W3l, const float* __restrict__ W3r,
                       u16* __restrict__ xb,
                       u16* __restrict__ wt1l, u16* __restrict__ wt1r,
                       u16* __restrict__ wt2l, u16* __restrict__ wt2r,
                       u16* __restrict__ wt3l, u16* __restrict__ wt3r, int N) {
    long idx = (long)blockIdx.x * 256 + threadIdx.x;
    long s0 = (long)N * 54;
    if (idx < s0) { xb[idx] = f2b(x[idx]); return; }
    idx -= s0;
    if (idx < 2 * 128 * 64) {
        u16* o = (idx < 128 * 64) ? wt1l : wt1r;
        const float* w = (idx < 128 * 64) ? W1l : W1r;
        long loc = idx % (128 * 64);
        int d = (int)(loc >> 6), k = (int)(loc & 63);
        o[loc] = (k < 54) ? f2b(w[(long)k * 128 + d]) : 0;
        return;
    }
    idx -= 2 * 128 * 64;
    if (idx < 2 * 256 * 128) {
        u16* o = (idx < 256 * 128) ? wt2l : wt2r;
        const float* w = (idx < 256 * 128) ? W2l : W2r;
        long loc = idx % (256 * 128);
        int d = (int)(loc >> 7), k = (int)(loc & 127);
        o[loc] = f2b(w[(long)k * 256 + d]);
        return;
    }
    idx -= 2 * 256 * 128;
    if (idx < 2 * 256 * 256) {
        u16* o = (idx < 256 * 256) ? wt3l : wt3r;
        const float* w = (idx < 256 * 256) ? W3l : W3r;
        long loc = idx % (256 * 256);
        int d = (int)(loc >> 8), k = (int)(loc & 255);
        o[loc] = f2b(w[(long)k * 256 + d]);
    }
}

// ---------------- CSR build ----------------
__global__ void k_count(const int* __restrict__ dst, int* __restrict__ cnt, int E) {
    int e = blockIdx.x * 256 + threadIdx.x;
    if (e < E) atomicAdd(&cnt[dst[e]], 1);
}

__global__ void k_bsum(const int* __restrict__ cnt, int* __restrict__ bsum, int N) {
    __shared__ int sm[256];
    int i = blockIdx.x * 256 + threadIdx.x;
    sm[threadIdx.x] = (i < N) ? cnt[i] : 0;
    __syncthreads();
    for (int off = 128; off > 0; off >>= 1) {
        if (threadIdx.x < off) sm[threadIdx.x] += sm[threadIdx.x + off];
        __syncthreads();
    }
    if (threadIdx.x == 0) bsum[blockIdx.x] = sm[0];
}

__global__ void k_bscan(const int* __restrict__ bsum, int* __restrict__ boff, int NB) {
    __shared__ int sm[256];
    int t = threadIdx.x;
    int v = (t < NB) ? bsum[t] : 0;
    sm[t] = v;
    __syncthreads();
    for (int off = 1; off < 256; off <<= 1) {
        int add = (t >= off) ? sm[t - off] : 0;
        __syncthreads();
        sm[t] += add;
        __syncthreads();
    }
    if (t < NB) boff[t] = sm[t] - v;  // exclusive
}

__global__ void k_scan(const int* __restrict__ cnt, const int* __restrict__ boff,
                       int* __restrict__ rowptr, int* __restrict__ wpos, int N, int E) {
    __shared__ int sm[256];
    int t = threadIdx.x;
    int i = blockIdx.x * 256 + t;
    int v = (i < N) ? cnt[i] : 0;
    sm[t] = v;
    __syncthreads();
    for (int off = 1; off < 256; off <<= 1) {
        int add = (t >= off) ? sm[t - off] : 0;
        __syncthreads();
        sm[t] += add;
        __syncthreads();
    }
    int ex = sm[t] - v + boff[blockIdx.x];
    if (i < N) { rowptr[i] = ex; wpos[i] = ex; }
    if (i == 0) rowptr[N] = E;
}

__global__ void k_fill(const int* __restrict__ src, const int* __restrict__ dst,
                       int* __restrict__ wpos, int* __restrict__ csr, int E) {
    int e = blockIdx.x * 256 + threadIdx.x;
    if (e < E) {
        int p = atomicAdd(&wpos[dst[e]], 1);
        csr[p] = src[e];
    }
}

// ---------------- aggregation (bf16 in/out, fp32 accum) ----------------
// one wave per node; VEC = bf16 elems per lane (4 / 2 / 1)
template <int D, int VEC>
__global__ __launch_bounds__(256) void k_agg(const u16* __restrict__ h,
                                             const int* __restrict__ rowptr,
                                             const int* __restrict__ csr,
                                             u16* __restrict__ agg, int n) {
    int w = threadIdx.x >> 6;
    int lane = threadIdx.x & 63;
    int i = blockIdx.x * 4 + w;
    if (i >= n) return;
    int b0 = rowptr[i], b1 = rowptr[i + 1];
    if constexpr (VEC == 4) {
        float a0 = 0.f, a1 = 0.f, a2 = 0.f, a3 = 0.f;
        #pragma unroll 4
        for (int b = b0; b < b1; ++b) {
            int s = csr[b];
            ushort4 v = *reinterpret_cast<const ushort4*>(h + (size_t)s * D + lane * 4);
            a0 += b2f(v.x); a1 += b2f(v.y); a2 += b2f(v.z); a3 += b2f(v.w);
        }
        ushort4 o; o.x = f2b(a0); o.y = f2b(a1); o.z = f2b(a2); o.w = f2b(a3);
        *reinterpret_cast<ushort4*>(agg + (size_t)i * D + lane * 4) = o;
    } else if constexpr (VEC == 2) {
        float a0 = 0.f, a1 = 0.f;
        #pragma unroll 4
        for (int b = b0; b < b1; ++b) {
            int s = csr[b];
            ushort2 v = *reinterpret_cast<const ushort2*>(h + (size_t)s * D + lane * 2);
            a0 += b2f(v.x); a1 += b2f(v.y);
        }
        ushort2 o; o.x = f2b(a0); o.y = f2b(a1);
        *reinterpret_cast<ushort2*>(agg + (size_t)i * D + lane * 2) = o;
    } else {
        if (lane < D) {
            float a0 = 0.f;
            #pragma unroll 4
            for (int b = b0; b < b1; ++b) {
                int s = csr[b];
                a0 += b2f(h[(size_t)s * D + lane]);
            }
            agg[(size_t)i * D + lane] = f2b(a0);
        }
    }
}

// ---------------- MFMA GEMM: C = relu(A1@W1 + A2@W2 + bias), bf16 in/out ----------------
template <int KA, int KW, int DOUT, bool A16>
__global__ __launch_bounds__(256) void k_mgemm(const u16* __restrict__ A1,
                                               const u16* __restrict__ A2,
                                               const u16* __restrict__ Wt1,
                                               const u16* __restrict__ Wt2,
                                               const float* __restrict__ bias,
                                               u16* __restrict__ C, int N) {
    constexpr int BM = 128, BKP = 40;      // LDS rows padded to 80B -> 2-way only
    __shared__ u16 As[BM * BKP];           // X tile   [128 nodes][32 k]
    __shared__ u16 Bs[BM * BKP];           // Wt tile  [128 feats][32 k]

    const int tid = threadIdx.x;
    const int w = tid >> 6, l = tid & 63;
    const int wr = w >> 1, wc = w & 1;     // wave grid 2x2
    const int lo = l & 15, hi = l >> 4;
    const int m0 = blockIdx.x * BM;
    const int n0 = blockIdx.y * 128;

    f32x4 acc[4][4];
    #pragma unroll
    for (int i = 0; i < 4; ++i)
        #pragma unroll
        for (int j = 0; j < 4; ++j) acc[i][j] = {0.f, 0.f, 0.f, 0.f};

    constexpr int KT = KW / 32;

    #pragma unroll
    for (int s = 0; s < 2; ++s) {
        const u16* __restrict__ Ap = s ? A2 : A1;
        const u16* __restrict__ Wp = s ? Wt2 : Wt1;
        for (int kt = 0; kt < KT; ++kt) {
            const int k0 = kt * 32;
            #pragma unroll
            for (int it = 0; it < 2; ++it) {
                int v = it * 256 + tid;
                int r = v >> 2, c = v & 3;
                uint4 val = *reinterpret_cast<const uint4*>(Wp + (size_t)(n0 + r) * KW + k0 + c * 8);
                *reinterpret_cast<uint4*>(&Bs[r * BKP + c * 8]) = val;
            }
            if constexpr (A16) {
                #pragma unroll
                for (int it = 0; it < 2; ++it) {
                    int v = it * 256 + tid;
                    int r = v >> 2, c = v & 3;
                    int m = m0 + r;
                    uint4 val = {0u, 0u, 0u, 0u};
                    if (m < N) val = *reinterpret_cast<const uint4*>(Ap + (size_t)m * KA + k0 + c * 8);
                    *reinterpret_cast<uint4*>(&As[r * BKP + c * 8]) = val;
                }
            } else {
                #pragma unroll
                for (int it = 0; it < 8; ++it) {
                    int v = it * 256 + tid;
                    int r = v >> 4, c = v & 15;
                    int m = m0 + r;
                    int k = k0 + c * 2;
                    unsigned val = 0;
                    if (m < N && k < KA)
                        val = *reinterpret_cast<const unsigned*>(Ap + (size_t)m * KA + k);
                    *reinterpret_cast<unsigned*>(&As[r * BKP + c * 2]) = val;
                }
            }
            __syncthreads();
            bf16x8 af[4], bf[4];
            #pragma unroll
            for (int f = 0; f < 4; ++f) {
                af[f] = *reinterpret_cast<const bf16x8*>(&Bs[(wc * 64 + f * 16 + lo) * BKP + hi * 8]);
                bf[f] = *reinterpret_cast<const bf16x8*>(&As[(wr * 64 + f * 16 + lo) * BKP + hi * 8]);
            }
            #pragma unroll
            for (int fm = 0; fm < 4; ++fm)
                #pragma unroll
                for (int fn = 0; fn < 4; ++fn)
                    acc[fm][fn] = __builtin_amdgcn_mfma_f32_16x16x32_bf16(af[fn], bf[fm], acc[fm][fn], 0, 0, 0);
            __syncthreads();
        }
    }
    #pragma unroll
    for (int fm = 0; fm < 4; ++fm) {
        int node = m0 + wr * 64 + fm * 16 + lo;
        if (node < N) {
            #pragma unroll
            for (int fn = 0; fn < 4; ++fn) {
                int fb = n0 + wc * 64 + fn * 16 + hi * 4;
                float4 bv = *reinterpret_cast<const float4*>(bias + fb);
                ushort4 o;
                o.x = f2b(fmaxf(acc[fm][fn][0] + bv.x, 0.f));
                o.y = f2b(fmaxf(acc[fm][fn][1] + bv.y, 0.f));
                o.z = f2b(fmaxf(acc[fm][fn][2] + bv.z, 0.f));
                o.w = f2b(fmaxf(acc[fm][fn][3] + bv.w, 0.f));
                *reinterpret_cast<ushort4*>(C + (size_t)node * DOUT + fb) = o;
            }
        }
    }
}

// ---------------- global mean pool (bf16 in, fp32 out) ----------------
// ROWS=32 rows per block -> ~1563 blocks (was 196 w/ 256 rows: latency-bound
// at 8% occupancy, 74us). batch sorted -> ~2 atomic flushes per block.
template <int ROWS>
__global__ void k_pool(const u16* __restrict__ h3, const int* __restrict__ batch,
                       float* __restrict__ outsum, int* __restrict__ cnt, int N) {
    int r0 = blockIdx.x * ROWS;
    int r1 = min(r0 + ROWS, N);
    if (r0 >= N) return;
    int d = threadIdx.x;
    int cur = batch[r0];
    float s = 0.f;
    int c = 0;
    for (int i = r0; i < r1; ++i) {
        int g = batch[i];  // uniform across block
        if (g != cur) {
            atomicAdd(&outsum[cur * 256 + d], s);
            if (d == 0) atomicAdd(&cnt[cur], c);
            s = 0.f; c = 0; cur = g;
        }
        s += b2f(h3[(size_t)i * 256 + d]);
        c++;
    }
    atomicAdd(&outsum[cur * 256 + d], s);
    if (d == 0) atomicAdd(&cnt[cur], c);
}

__global__ void k_div(float* __restrict__ out, const int* __restrict__ cnt, int total) {
    int idx = blockIdx.x * 256 + threadIdx.x;
    if (idx < total) {
        float c = fmaxf((float)cnt[idx >> 8], 1.0f);
        out[idx] = out[idx] / c;
    }
}

// ---------------------------------------------------------------------------
extern "C" void kernel_launch(void* const* d_in, const int* in_sizes, int n_in,
                              void* d_out, int out_size, void* d_ws, size_t ws_size,
                              hipStream_t stream) {
    const float* x   = (const float*)d_in[0];
    const int* ei    = (const int*)d_in[1];
    const int* batch = (const int*)d_in[2];
    const float* W1l = (const float*)d_in[3];
    const float* b1  = (const float*)d_in[4];
    const float* W1r = (const float*)d_in[5];
    const float* W2l = (const float*)d_in[6];
    const float* b2  = (const float*)d_in[7];
    const float* W2r = (const float*)d_in[8];
    const float* W3l = (const float*)d_in[9];
    const float* b3  = (const float*)d_in[10];
    const float* W3r = (const float*)d_in[11];

    const int N = in_sizes[0] / 54;
    const int E = in_sizes[1] / 2;
    const int* src = ei;
    const int* dst = ei + E;

    // workspace layout (bf16 = u16)
    u16* xb   = (u16*)d_ws;                       // N*54
    u16* bufA = xb + (size_t)N * 54;              // agg out, N*256 max
    u16* buf1 = bufA + (size_t)N * 256;           // h1 / h3
    u16* buf2 = buf1 + (size_t)N * 256;           // h2
    u16* wt1l = buf2 + (size_t)N * 256;           // [128][64]
    u16* wt1r = wt1l + 128 * 64;
    u16* wt2l = wt1r + 128 * 64;                  // [256][128]
    u16* wt2r = wt2l + 256 * 128;
    u16* wt3l = wt2r + 256 * 128;                 // [256][256]
    u16* wt3r = wt3l + 256 * 256;
    int* ip = (int*)(wt3r + 256 * 256);
    int* cntdeg  = ip; ip += N;
    int* rowptr  = ip; ip += N + 1;
    int* wpos    = ip; ip += N + 1;
    int* bsum    = ip; ip += 256;
    int* boff    = ip; ip += 256;
    int* cntpool = ip; ip += 128;
    int* csr     = ip;                            // E ints

    hipMemsetAsync(cntdeg, 0, (size_t)N * sizeof(int), stream);
    hipMemsetAsync(d_out, 0, (size_t)out_size * sizeof(float), stream);
    hipMemsetAsync(cntpool, 0, 128 * sizeof(int), stream);

    const int NB = (N + 255) / 256;
    const int EB = (E + 255) / 256;

    // prep: bf16 conversions + weight transposes
    {
        long total = (long)N * 54 + 2L * 128 * 64 + 2L * 256 * 128 + 2L * 256 * 256;
        int g = (int)((total + 255) / 256);
        k_prep<<<g, 256, 0, stream>>>(x, W1l, W1r, W2l, W2r, W3l, W3r,
                                      xb, wt1l, wt1r, wt2l, wt2r, wt3l, wt3r, N);
    }

    // CSR build
    k_count<<<EB, 256, 0, stream>>>(dst, cntdeg, E);
    k_bsum<<<NB, 256, 0, stream>>>(cntdeg, bsum, N);
    k_bscan<<<1, 256, 0, stream>>>(bsum, boff, NB);
    k_scan<<<NB, 256, 0, stream>>>(cntdeg, boff, rowptr, wpos, N, E);
    k_fill<<<EB, 256, 0, stream>>>(src, dst, wpos, csr, E);

    const int AGB = (N + 3) / 4;
    const int GX = (N + 127) / 128;

    // layer 1: 54 -> 128
    k_agg<54, 1><<<AGB, 256, 0, stream>>>(xb, rowptr, csr, bufA, N);
    {
        dim3 g(GX, 1);
        k_mgemm<54, 64, 128, false><<<g, 256, 0, stream>>>(bufA, xb, wt1l, wt1r, b1, buf1, N);
    }
    // layer 2: 128 -> 256
    k_agg<128, 2><<<AGB, 256, 0, stream>>>(buf1, rowptr, csr, bufA, N);
    {
        dim3 g(GX, 2);
        k_mgemm<128, 128, 256, true><<<g, 256, 0, stream>>>(bufA, buf1, wt2l, wt2r, b2, buf2, N);
    }
    // layer 3: 256 -> 256
    k_agg<256, 4><<<AGB, 256, 0, stream>>>(buf2, rowptr, csr, bufA, N);
    {
        dim3 g(GX, 2);
        k_mgemm<256, 256, 256, true><<<g, 256, 0, stream>>>(bufA, buf2, wt3l, wt3r, b3, buf1, N);
    }

    // global mean pool
    k_pool<32><<<(N + 31) / 32, 256, 0, stream>>>(buf1, batch, (float*)d_out, cntpool, N);
    k_div<<<(out_size + 255) / 256, 256, 0, stream>>>((float*)d_out, cntpool, out_size);
}

// Round 6
// 349.525 us; speedup vs baseline: 3.2293x; 1.0263x over previous
//
#include <hip/hip_runtime.h>

// ---------------------------------------------------------------------------
// GraphSAGE x3 (sum aggr) + global mean pool.
// bf16 storage + MFMA 16x16x32 GEMMs (fp32 accum). Threshold is bf16-scaled.
// Pipeline: prep (bf16 cvt + weight transpose) -> CSR -> [agg -> MFMA GEMM] x3 -> pool
// ---------------------------------------------------------------------------

typedef unsigned short u16;
typedef __attribute__((ext_vector_type(8))) short bf16x8;
typedef __attribute__((ext_vector_type(4))) float f32x4;

__device__ __forceinline__ u16 f2b(float f) {
    union { float f; unsigned u; } v; v.f = f;
    unsigned u = v.u;
    return (u16)((u + 0x7FFF + ((u >> 16) & 1)) >> 16);   // RNE
}
__device__ __forceinline__ float b2f(u16 h) {
    union { unsigned u; float f; } v; v.u = ((unsigned)h) << 16;
    return v.f;
}
__device__ __forceinline__ float blo(unsigned u) {   // low bf16 of a u32 pair
    union { unsigned u; float f; } v; v.u = u << 16;
    return v.f;
}
__device__ __forceinline__ float bhi(unsigned u) {   // high bf16 of a u32 pair
    union { unsigned u; float f; } v; v.u = u & 0xffff0000u;
    return v.f;
}

// ---------------- prep: x -> bf16, weights -> bf16 transposed [D][KP] ----------------
__global__ void k_prep(const float* __restrict__ x,
                       const float* __restrict__ W1l, const float* __restrict__ W1r,
                       const float* __restrict__ W2l, const float* __restrict__ W2r,
                       const float* __restrict__ W3l, const float* __restrict__ W3r,
                       u16* __restrict__ xb,
                       u16* __restrict__ wt1l, u16* __restrict__ wt1r,
                       u16* __restrict__ wt2l, u16* __restrict__ wt2r,
                       u16* __restrict__ wt3l, u16* __restrict__ wt3r, int N) {
    long idx = (long)blockIdx.x * 256 + threadIdx.x;
    long s0 = (long)N * 54;
    if (idx < s0) { xb[idx] = f2b(x[idx]); return; }
    idx -= s0;
    if (idx < 2 * 128 * 64) {
        u16* o = (idx < 128 * 64) ? wt1l : wt1r;
        const float* w = (idx < 128 * 64) ? W1l : W1r;
        long loc = idx % (128 * 64);
        int d = (int)(loc >> 6), k = (int)(loc & 63);
        o[loc] = (k < 54) ? f2b(w[(long)k * 128 + d]) : 0;
        return;
    }
    idx -= 2 * 128 * 64;
    if (idx < 2 * 256 * 128) {
        u16* o = (idx < 256 * 128) ? wt2l : wt2r;
        const float* w = (idx < 256 * 128) ? W2l : W2r;
        long loc = idx % (256 * 128);
        int d = (int)(loc >> 7), k = (int)(loc & 127);
        o[loc] = f2b(w[(long)k * 256 + d]);
        return;
    }
    idx -= 2 * 256 * 128;
    if (idx < 2 * 256 * 256) {
        u16* o = (idx < 256 * 256) ? wt3l : wt3r;
        const float* w = (idx < 256 * 256) ? W3l : W3r;
        long loc = idx % (256 * 256);
        int d = (int)(loc >> 8), k = (int)(loc & 255);
        o[loc] = f2b(w[(long)k * 256 + d]);
    }
}

// ---------------- CSR build ----------------
__global__ void k_count(const int* __restrict__ dst, int* __restrict__ cnt, int E) {
    int e = blockIdx.x * 256 + threadIdx.x;
    if (e < E) atomicAdd(&cnt[dst[e]], 1);
}

__global__ void k_bsum(const int* __restrict__ cnt, int* __restrict__ bsum, int N) {
    __shared__ int sm[256];
    int i = blockIdx.x * 256 + threadIdx.x;
    sm[threadIdx.x] = (i < N) ? cnt[i] : 0;
    __syncthreads();
    for (int off = 128; off > 0; off >>= 1) {
        if (threadIdx.x < off) sm[threadIdx.x] += sm[threadIdx.x + off];
        __syncthreads();
    }
    if (threadIdx.x == 0) bsum[blockIdx.x] = sm[0];
}

__global__ void k_bscan(const int* __restrict__ bsum, int* __restrict__ boff, int NB) {
    __shared__ int sm[256];
    int t = threadIdx.x;
    int v = (t < NB) ? bsum[t] : 0;
    sm[t] = v;
    __syncthreads();
    for (int off = 1; off < 256; off <<= 1) {
        int add = (t >= off) ? sm[t - off] : 0;
        __syncthreads();
        sm[t] += add;
        __syncthreads();
    }
    if (t < NB) boff[t] = sm[t] - v;  // exclusive
}

__global__ void k_scan(const int* __restrict__ cnt, const int* __restrict__ boff,
                       int* __restrict__ rowptr, int* __restrict__ wpos, int N, int E) {
    __shared__ int sm[256];
    int t = threadIdx.x;
    int i = blockIdx.x * 256 + t;
    int v = (i < N) ? cnt[i] : 0;
    sm[t] = v;
    __syncthreads();
    for (int off = 1; off < 256; off <<= 1) {
        int add = (t >= off) ? sm[t - off] : 0;
        __syncthreads();
        sm[t] += add;
        __syncthreads();
    }
    int ex = sm[t] - v + boff[blockIdx.x];
    if (i < N) { rowptr[i] = ex; wpos[i] = ex; }
    if (i == 0) rowptr[N] = E;
}

__global__ void k_fill(const int* __restrict__ src, const int* __restrict__ dst,
                       int* __restrict__ wpos, int* __restrict__ csr, int E) {
    int e = blockIdx.x * 256 + threadIdx.x;
    if (e < E) {
        int p = atomicAdd(&wpos[dst[e]], 1);
        csr[p] = src[e];
    }
}

// ---------------- aggregation, scalar variant (layer 1, D=54) ----------------
__global__ __launch_bounds__(256) void k_agg54(const u16* __restrict__ h,
                                               const int* __restrict__ rowptr,
                                               const int* __restrict__ csr,
                                               u16* __restrict__ agg, int n) {
    constexpr int D = 54;
    int w = threadIdx.x >> 6;
    int lane = threadIdx.x & 63;
    int i = blockIdx.x * 4 + w;
    if (i >= n) return;
    int b0 = rowptr[i], b1 = rowptr[i + 1];
    if (lane < D) {
        float a0 = 0.f;
        #pragma unroll 8
        for (int b = b0; b < b1; ++b) {
            int s = csr[b];
            a0 += b2f(h[(size_t)s * D + lane]);
        }
        agg[(size_t)i * D + lane] = f2b(a0);
    }
}

// ---------------- aggregation, multi-edge vector variant ----------------
// One wave per node. Each iteration processes EPW edges: lanes split into EPW
// groups of GRP=64/EPW lanes; each lane loads 16B (8 bf16) of its edge's row.
// D = GRP*8. Cross-group merge via shfl_xor once per node.
template <int D, int EPW>
__global__ __launch_bounds__(256) void k_aggv(const u16* __restrict__ h,
                                              const int* __restrict__ rowptr,
                                              const int* __restrict__ csr,
                                              u16* __restrict__ agg, int n) {
    constexpr int GRP = 64 / EPW;          // lanes per edge
    static_assert(D == GRP * 8, "geometry");
    int w = threadIdx.x >> 6;
    int lane = threadIdx.x & 63;
    int i = blockIdx.x * 4 + w;
    if (i >= n) return;
    int b0 = rowptr[i], b1 = rowptr[i + 1];
    int sub = lane / GRP;                  // which edge of the pack
    int dl = lane % GRP;                   // which 16B chunk of the row

    float a0 = 0.f, a1 = 0.f, a2 = 0.f, a3 = 0.f;
    float a4 = 0.f, a5 = 0.f, a6 = 0.f, a7 = 0.f;

    int b = b0;
    #pragma unroll 4
    for (; b + EPW <= b1; b += EPW) {
        int s = csr[b + sub];
        uint4 v = *reinterpret_cast<const uint4*>(h + (size_t)s * D + dl * 8);
        a0 += blo(v.x); a1 += bhi(v.x);
        a2 += blo(v.y); a3 += bhi(v.y);
        a4 += blo(v.z); a5 += bhi(v.z);
        a6 += blo(v.w); a7 += bhi(v.w);
    }
    int rem = b1 - b;
    if (sub < rem) {
        int s = csr[b + sub];
        uint4 v = *reinterpret_cast<const uint4*>(h + (size_t)s * D + dl * 8);
        a0 += blo(v.x); a1 += bhi(v.x);
        a2 += blo(v.y); a3 += bhi(v.y);
        a4 += blo(v.z); a5 += bhi(v.z);
        a6 += blo(v.w); a7 += bhi(v.w);
    }
    // merge the EPW partial groups (lane ^ GRP, ... , lane ^ 32)
    #pragma unroll
    for (int off = GRP; off < 64; off <<= 1) {
        a0 += __shfl_xor(a0, off, 64);
        a1 += __shfl_xor(a1, off, 64);
        a2 += __shfl_xor(a2, off, 64);
        a3 += __shfl_xor(a3, off, 64);
        a4 += __shfl_xor(a4, off, 64);
        a5 += __shfl_xor(a5, off, 64);
        a6 += __shfl_xor(a6, off, 64);
        a7 += __shfl_xor(a7, off, 64);
    }
    if (sub == 0) {
        uint4 o;
        o.x = ((unsigned)f2b(a0)) | (((unsigned)f2b(a1)) << 16);
        o.y = ((unsigned)f2b(a2)) | (((unsigned)f2b(a3)) << 16);
        o.z = ((unsigned)f2b(a4)) | (((unsigned)f2b(a5)) << 16);
        o.w = ((unsigned)f2b(a6)) | (((unsigned)f2b(a7)) << 16);
        *reinterpret_cast<uint4*>(agg + (size_t)i * D + dl * 8) = o;
    }
}

// ---------------- MFMA GEMM: C = relu(A1@W1 + A2@W2 + bias), bf16 in/out ----------------
template <int KA, int KW, int DOUT, bool A16>
__global__ __launch_bounds__(256) void k_mgemm(const u16* __restrict__ A1,
                                               const u16* __restrict__ A2,
                                               const u16* __restrict__ Wt1,
                                               const u16* __restrict__ Wt2,
                                               const float* __restrict__ bias,
                                               u16* __restrict__ C, int N) {
    constexpr int BM = 128, BKP = 40;      // LDS rows padded to 80B -> 2-way only
    __shared__ u16 As[BM * BKP];           // X tile   [128 nodes][32 k]
    __shared__ u16 Bs[BM * BKP];           // Wt tile  [128 feats][32 k]

    const int tid = threadIdx.x;
    const int w = tid >> 6, l = tid & 63;
    const int wr = w >> 1, wc = w & 1;     // wave grid 2x2
    const int lo = l & 15, hi = l >> 4;
    const int m0 = blockIdx.x * BM;
    const int n0 = blockIdx.y * 128;

    f32x4 acc[4][4];
    #pragma unroll
    for (int i = 0; i < 4; ++i)
        #pragma unroll
        for (int j = 0; j < 4; ++j) acc[i][j] = {0.f, 0.f, 0.f, 0.f};

    constexpr int KT = KW / 32;

    #pragma unroll
    for (int s = 0; s < 2; ++s) {
        const u16* __restrict__ Ap = s ? A2 : A1;
        const u16* __restrict__ Wp = s ? Wt2 : Wt1;
        for (int kt = 0; kt < KT; ++kt) {
            const int k0 = kt * 32;
            #pragma unroll
            for (int it = 0; it < 2; ++it) {
                int v = it * 256 + tid;
                int r = v >> 2, c = v & 3;
                uint4 val = *reinterpret_cast<const uint4*>(Wp + (size_t)(n0 + r) * KW + k0 + c * 8);
                *reinterpret_cast<uint4*>(&Bs[r * BKP + c * 8]) = val;
            }
            if constexpr (A16) {
                #pragma unroll
                for (int it = 0; it < 2; ++it) {
                    int v = it * 256 + tid;
                    int r = v >> 2, c = v & 3;
                    int m = m0 + r;
                    uint4 val = {0u, 0u, 0u, 0u};
                    if (m < N) val = *reinterpret_cast<const uint4*>(Ap + (size_t)m * KA + k0 + c * 8);
                    *reinterpret_cast<uint4*>(&As[r * BKP + c * 8]) = val;
                }
            } else {
                #pragma unroll
                for (int it = 0; it < 8; ++it) {
                    int v = it * 256 + tid;
                    int r = v >> 4, c = v & 15;
                    int m = m0 + r;
                    int k = k0 + c * 2;
                    unsigned val = 0;
                    if (m < N && k < KA)
                        val = *reinterpret_cast<const unsigned*>(Ap + (size_t)m * KA + k);
                    *reinterpret_cast<unsigned*>(&As[r * BKP + c * 2]) = val;
                }
            }
            __syncthreads();
            bf16x8 af[4], bf[4];
            #pragma unroll
            for (int f = 0; f < 4; ++f) {
                af[f] = *reinterpret_cast<const bf16x8*>(&Bs[(wc * 64 + f * 16 + lo) * BKP + hi * 8]);
                bf[f] = *reinterpret_cast<const bf16x8*>(&As[(wr * 64 + f * 16 + lo) * BKP + hi * 8]);
            }
            #pragma unroll
            for (int fm = 0; fm < 4; ++fm)
                #pragma unroll
                for (int fn = 0; fn < 4; ++fn)
                    acc[fm][fn] = __builtin_amdgcn_mfma_f32_16x16x32_bf16(af[fn], bf[fm], acc[fm][fn], 0, 0, 0);
            __syncthreads();
        }
    }
    #pragma unroll
    for (int fm = 0; fm < 4; ++fm) {
        int node = m0 + wr * 64 + fm * 16 + lo;
        if (node < N) {
            #pragma unroll
            for (int fn = 0; fn < 4; ++fn) {
                int fb = n0 + wc * 64 + fn * 16 + hi * 4;
                float4 bv = *reinterpret_cast<const float4*>(bias + fb);
                ushort4 o;
                o.x = f2b(fmaxf(acc[fm][fn][0] + bv.x, 0.f));
                o.y = f2b(fmaxf(acc[fm][fn][1] + bv.y, 0.f));
                o.z = f2b(fmaxf(acc[fm][fn][2] + bv.z, 0.f));
                o.w = f2b(fmaxf(acc[fm][fn][3] + bv.w, 0.f));
                *reinterpret_cast<ushort4*>(C + (size_t)node * DOUT + fb) = o;
            }
        }
    }
}

// ---------------- global mean pool (bf16 in, fp32 out) ----------------
template <int ROWS>
__global__ void k_pool(const u16* __restrict__ h3, const int* __restrict__ batch,
                       float* __restrict__ outsum, int* __restrict__ cnt, int N) {
    int r0 = blockIdx.x * ROWS;
    int r1 = min(r0 + ROWS, N);
    if (r0 >= N) return;
    int d = threadIdx.x;
    int cur = batch[r0];
    float s = 0.f;
    int c = 0;
    for (int i = r0; i < r1; ++i) {
        int g = batch[i];  // uniform across block
        if (g != cur) {
            atomicAdd(&outsum[cur * 256 + d], s);
            if (d == 0) atomicAdd(&cnt[cur], c);
            s = 0.f; c = 0; cur = g;
        }
        s += b2f(h3[(size_t)i * 256 + d]);
        c++;
    }
    atomicAdd(&outsum[cur * 256 + d], s);
    if (d == 0) atomicAdd(&cnt[cur], c);
}

__global__ void k_div(float* __restrict__ out, const int* __restrict__ cnt, int total) {
    int idx = blockIdx.x * 256 + threadIdx.x;
    if (idx < total) {
        float c = fmaxf((float)cnt[idx >> 8], 1.0f);
        out[idx] = out[idx] / c;
    }
}

// ---------------------------------------------------------------------------
extern "C" void kernel_launch(void* const* d_in, const int* in_sizes, int n_in,
                              void* d_out, int out_size, void* d_ws, size_t ws_size,
                              hipStream_t stream) {
    const float* x   = (const float*)d_in[0];
    const int* ei    = (const int*)d_in[1];
    const int* batch = (const int*)d_in[2];
    const float* W1l = (const float*)d_in[3];
    const float* b1  = (const float*)d_in[4];
    const float* W1r = (const float*)d_in[5];
    const float* W2l = (const float*)d_in[6];
    const float* b2  = (const float*)d_in[7];
    const float* W2r = (const float*)d_in[8];
    const float* W3l = (const float*)d_in[9];
    const float* b3  = (const float*)d_in[10];
    const float* W3r = (const float*)d_in[11];

    const int N = in_sizes[0] / 54;
    const int E = in_sizes[1] / 2;
    const int* src = ei;
    const int* dst = ei + E;

    // workspace layout (bf16 = u16)
    u16* xb   = (u16*)d_ws;                       // N*54
    u16* bufA = xb + (size_t)N * 54;              // agg out, N*256 max
    u16* buf1 = bufA + (size_t)N * 256;           // h1 / h3
    u16* buf2 = buf1 + (size_t)N * 256;           // h2
    u16* wt1l = buf2 + (size_t)N * 256;           // [128][64]
    u16* wt1r = wt1l + 128 * 64;
    u16* wt2l = wt1r + 128 * 64;                  // [256][128]
    u16* wt2r = wt2l + 256 * 128;
    u16* wt3l = wt2r + 256 * 128;                 // [256][256]
    u16* wt3r = wt3l + 256 * 256;
    int* ip = (int*)(wt3r + 256 * 256);
    int* cntdeg  = ip; ip += N;
    int* rowptr  = ip; ip += N + 1;
    int* wpos    = ip; ip += N + 1;
    int* bsum    = ip; ip += 256;
    int* boff    = ip; ip += 256;
    int* cntpool = ip; ip += 128;
    int* csr     = ip;                            // E ints

    hipMemsetAsync(cntdeg, 0, (size_t)N * sizeof(int), stream);
    hipMemsetAsync(d_out, 0, (size_t)out_size * sizeof(float), stream);
    hipMemsetAsync(cntpool, 0, 128 * sizeof(int), stream);

    const int NB = (N + 255) / 256;
    const int EB = (E + 255) / 256;

    // prep: bf16 conversions + weight transposes
    {
        long total = (long)N * 54 + 2L * 128 * 64 + 2L * 256 * 128 + 2L * 256 * 256;
        int g = (int)((total + 255) / 256);
        k_prep<<<g, 256, 0, stream>>>(x, W1l, W1r, W2l, W2r, W3l, W3r,
                                      xb, wt1l, wt1r, wt2l, wt2r, wt3l, wt3r, N);
    }

    // CSR build
    k_count<<<EB, 256, 0, stream>>>(dst, cntdeg, E);
    k_bsum<<<NB, 256, 0, stream>>>(cntdeg, bsum, N);
    k_bscan<<<1, 256, 0, stream>>>(bsum, boff, NB);
    k_scan<<<NB, 256, 0, stream>>>(cntdeg, boff, rowptr, wpos, N, E);
    k_fill<<<EB, 256, 0, stream>>>(src, dst, wpos, csr, E);

    const int AGB = (N + 3) / 4;
    const int GX = (N + 127) / 128;

    // layer 1: 54 -> 128
    k_agg54<<<AGB, 256, 0, stream>>>(xb, rowptr, csr, bufA, N);
    {
        dim3 g(GX, 1);
        k_mgemm<54, 64, 128, false><<<g, 256, 0, stream>>>(bufA, xb, wt1l, wt1r, b1, buf1, N);
    }
    // layer 2: 128 -> 256   (gather 16B/lane, 4 edges per wave-iter)
    k_aggv<128, 4><<<AGB, 256, 0, stream>>>(buf1, rowptr, csr, bufA, N);
    {
        dim3 g(GX, 2);
        k_mgemm<128, 128, 256, true><<<g, 256, 0, stream>>>(bufA, buf1, wt2l, wt2r, b2, buf2, N);
    }
    // layer 3: 256 -> 256   (gather 16B/lane, 2 edges per wave-iter)
    k_aggv<256, 2><<<AGB, 256, 0, stream>>>(buf2, rowptr, csr, bufA, N);
    {
        dim3 g(GX, 2);
        k_mgemm<256, 256, 256, true><<<g, 256, 0, stream>>>(bufA, buf2, wt3l, wt3r, b3, buf1, N);
    }

    // global mean pool
    k_pool<32><<<(N + 31) / 32, 256, 0, stream>>>(buf1, batch, (float*)d_out, cntpool, N);
    k_div<<<(out_size + 255) / 256, 256, 0, stream>>>((float*)d_out, cntpool, out_size);
}